// Round 2
// baseline (1351.654 us; speedup 1.0000x reference)
//
#include <hip/hip_runtime.h>
#include <hip/hip_bf16.h>

typedef __bf16 bf16;
typedef __bf16 bf16x8 __attribute__((ext_vector_type(8)));
typedef float f32x4 __attribute__((ext_vector_type(4)));

#define NB_ 6
#define E_ 512
#define NH_ 8
#define HS_ 64
#define FF_ 2048
#define B_ 16
#define T_ 512
#define M_ 8192   // B*T

typedef const __attribute__((address_space(1))) void* gptr_t;
typedef __attribute__((address_space(3))) void* sptr_t;

// ---------------------------------------------------------------- weight prep
// wq/wk/wv [i][h][e][d] -> dst[i][c][e], c = which*512 + h*64 + d (bf16)
__global__ __launch_bounds__(256) void conv_qkv_tiled(
    const float* __restrict__ wq, const float* __restrict__ wk,
    const float* __restrict__ wv, bf16* __restrict__ dst)
{
    __shared__ float tile[32][65];          // [e][d], pad to 65
    const int e0 = blockIdx.x * 32;
    const int wh = blockIdx.y;              // 0..23
    const int which = wh >> 3, h = wh & 7;
    const int i = blockIdx.z;
    const float* src = (which == 0) ? wq : (which == 1) ? wk : wv;
    src += (((size_t)i * NH_ + h) * E_ + e0) * HS_;
    const int d = threadIdx.x & 63, er = threadIdx.x >> 6;    // 4 e-rows/pass
#pragma unroll
    for (int j = 0; j < 32; j += 4)
        tile[j + er][d] = src[(size_t)(j + er) * HS_ + d];
    __syncthreads();
    const int e = threadIdx.x & 31, dr = threadIdx.x >> 5;    // 8 d-rows/pass
    bf16* dbase = dst + (size_t)i * 1536 * E_ + ((size_t)which * 512 + h * 64) * E_ + e0;
#pragma unroll
    for (int j = 0; j < 64; j += 8)
        dbase[(size_t)(j + dr) * E_ + e] = (bf16)tile[e][j + dr];
}

// src[i][K][N] f32 -> dst[i][N][K] bf16 (tiled, coalesced both sides)
__global__ __launch_bounds__(256) void transpose_tiled(
    const float* __restrict__ src, bf16* __restrict__ dst, int K, int N)
{
    __shared__ float tile[32][33];
    const int n0 = blockIdx.x * 32, k0 = blockIdx.y * 32;
    const size_t sb = (size_t)blockIdx.z * K * N;
    const int lx = threadIdx.x & 31, ly = threadIdx.x >> 5;   // 8 rows/pass
#pragma unroll
    for (int j = 0; j < 32; j += 8)
        tile[j + ly][lx] = src[sb + (size_t)(k0 + j + ly) * N + n0 + lx];
    __syncthreads();
#pragma unroll
    for (int j = 0; j < 32; j += 8)
        dst[sb + (size_t)(n0 + j + ly) * K + k0 + lx] = (bf16)tile[lx][j + ly];
}

// ---------------------------------------------------------------- embed
__global__ __launch_bounds__(256) void embed_kernel(
    const int* __restrict__ x, const float* __restrict__ emb,
    const float* __restrict__ pos, float* __restrict__ h)
{
    int idx = blockIdx.x * 256 + threadIdx.x;   // per float4, M*128 total
    int row = idx >> 7;
    int e4 = (idx & 127) << 2;
    int tok = x[row];
    int t = row & (T_ - 1);
    int p = t;                                  // min(t, L-1), L==T
    float4 a = *(const float4*)&emb[(size_t)tok * E_ + e4];
    float4 c = *(const float4*)&pos[(size_t)p * E_ + e4];
    float4 o; o.x = a.x + c.x; o.y = a.y + c.y; o.z = a.z + c.z; o.w = a.w + c.w;
    *(float4*)&h[(size_t)row * E_ + e4] = o;
}

// ---------------------------------------------------------------- layernorm
template<int OUT_F32>
__global__ __launch_bounds__(256) void ln_kernel(
    const float* __restrict__ x, const float* __restrict__ gw,
    const float* __restrict__ bw, void* __restrict__ out)
{
    int wave = threadIdx.x >> 6, lane = threadIdx.x & 63;
    int row = blockIdx.x * 4 + wave;
    const float* xr = x + (size_t)row * E_;
    float4 v0 = *(const float4*)&xr[lane * 8];
    float4 v1 = *(const float4*)&xr[lane * 8 + 4];
    float vals[8] = {v0.x, v0.y, v0.z, v0.w, v1.x, v1.y, v1.z, v1.w};
    float s = 0.f, ss = 0.f;
#pragma unroll
    for (int j = 0; j < 8; ++j) { s += vals[j]; ss += vals[j] * vals[j]; }
#pragma unroll
    for (int m = 1; m < 64; m <<= 1) { s += __shfl_xor(s, m, 64); ss += __shfl_xor(ss, m, 64); }
    float mu = s * (1.f / E_);
    float var = ss * (1.f / E_) - mu * mu;
    float rs = rsqrtf(var + 1e-5f);
    int e0 = lane * 8;
    if (OUT_F32) {
        float* o = (float*)out + (size_t)row * E_ + e0;
#pragma unroll
        for (int j = 0; j < 8; ++j) o[j] = (vals[j] - mu) * rs * gw[e0 + j] + bw[e0 + j];
    } else {
        bf16x8 o;
#pragma unroll
        for (int j = 0; j < 8; ++j) o[j] = (bf16)((vals[j] - mu) * rs * gw[e0 + j] + bw[e0 + j]);
        *(bf16x8*)&((bf16*)out)[(size_t)row * E_ + e0] = o;
    }
}

// ---------------------------------------------------------------- GEMM (A[M][K] x Bt[N][K]^T)
template<int HAS_BIAS, int HAS_RES, int RELU, int OUT_BF16>
__global__ __launch_bounds__(256) void gemm_bt(
    const bf16* __restrict__ A, const bf16* __restrict__ Bt,
    const float* __restrict__ bias, const float* __restrict__ res,
    void* __restrict__ out, int M, int N, int K)
{
    constexpr int BM = 128, BN = 128, BK = 32;
    __shared__ bf16 As[BM * BK];
    __shared__ bf16 Bs[BN * BK];
    const int tid = threadIdx.x;
    const int wave = tid >> 6, lane = tid & 63;
    const int l15 = lane & 15, g = lane >> 4;
    const int n0 = blockIdx.x * BN, m0 = blockIdx.y * BM;
    const int wm = (wave >> 1) * 64, wn = (wave & 1) * 64;
    // staging indices: LDS byte offset = idx*16 — linear in tid (required for global_load_lds)
    const int srow = tid >> 2, sc8 = (tid & 3) << 3;
    f32x4 acc[4][4] = {};
    for (int k0 = 0; k0 < K; k0 += BK) {
        __syncthreads();
#pragma unroll
        for (int r = 0; r < 2; ++r) {
            int row = srow + r * 64;
            __builtin_amdgcn_global_load_lds(
                (gptr_t)&A[(size_t)(m0 + row) * K + k0 + sc8],
                (sptr_t)&As[row * BK + sc8], 16, 0, 0);
        }
#pragma unroll
        for (int r = 0; r < 2; ++r) {
            int row = srow + r * 64;
            __builtin_amdgcn_global_load_lds(
                (gptr_t)&Bt[(size_t)(n0 + row) * K + k0 + sc8],
                (sptr_t)&Bs[row * BK + sc8], 16, 0, 0);
        }
        __syncthreads();
        bf16x8 af[4], bg[4];
#pragma unroll
        for (int mi = 0; mi < 4; ++mi)
            af[mi] = *(const bf16x8*)&As[(wm + 16 * mi + l15) * BK + 8 * g];
#pragma unroll
        for (int ni = 0; ni < 4; ++ni)
            bg[ni] = *(const bf16x8*)&Bs[(wn + 16 * ni + l15) * BK + 8 * g];
#pragma unroll
        for (int mi = 0; mi < 4; ++mi)
#pragma unroll
            for (int ni = 0; ni < 4; ++ni)
                acc[mi][ni] = __builtin_amdgcn_mfma_f32_16x16x32_bf16(
                    af[mi], bg[ni], acc[mi][ni], 0, 0, 0);
    }
    // epilogue: C/D layout col=lane&15, row=(lane>>4)*4+reg  [measured m89]
#pragma unroll
    for (int mi = 0; mi < 4; ++mi) {
#pragma unroll
        for (int ni = 0; ni < 4; ++ni) {
#pragma unroll
            for (int r = 0; r < 4; ++r) {
                int rr = m0 + wm + 16 * mi + 4 * g + r;
                int cc = n0 + wn + 16 * ni + l15;
                float v = acc[mi][ni][r];
                if (HAS_BIAS) v += bias[cc];
                if (HAS_RES) v += res[(size_t)rr * N + cc];
                if (RELU) v = fmaxf(v, 0.f);
                if (OUT_BF16) ((bf16*)out)[(size_t)rr * N + cc] = (bf16)v;
                else ((float*)out)[(size_t)rr * N + cc] = v;
            }
        }
    }
}

// ---------------------------------------------------------------- attention
// qkv: [B*T][1536] bf16 (q|k|v, each col = h*64+d). out: [B*T][512] bf16.
__global__ __launch_bounds__(256) void attn_kernel(
    const bf16* __restrict__ qkv, bf16* __restrict__ out)
{
    constexpr int RS = 3 * E_;   // 1536 row stride
    __shared__ bf16 Ks[64 * 64];
    __shared__ bf16 Vt[64 * 64];
    __shared__ bf16 Ps[4][16 * 64];
    const int tid = threadIdx.x;
    const int wave = tid >> 6, lane = tid & 63;
    const int l15 = lane & 15, g = lane >> 4;
    const int q0 = blockIdx.x * 64;
    const int bh = blockIdx.y;
    const int b = bh >> 3, h = bh & 7;
    const size_t base = (size_t)b * T_ * RS;

    bf16x8 qf[2];
    {
        const bf16* qrow = qkv + base + (size_t)(q0 + wave * 16 + l15) * RS + h * HS_;
        qf[0] = *(const bf16x8*)&qrow[8 * g];
        qf[1] = *(const bf16x8*)&qrow[32 + 8 * g];
    }
    float mrow[4] = {-1e30f, -1e30f, -1e30f, -1e30f};
    float lrow[4] = {0.f, 0.f, 0.f, 0.f};
    f32x4 accO[4] = {};
    const int ntiles = blockIdx.x + 1;
    for (int tile = 0; tile < ntiles; ++tile) {
        const int kv0 = tile * 64;
        __syncthreads();
#pragma unroll
        for (int r = 0; r < 2; ++r) {
            int idx = r * 256 + tid;
            int krow = idx >> 3, c8 = (idx & 7) << 3;
            const bf16* ksrc = qkv + base + (size_t)(kv0 + krow) * RS + E_ + h * HS_ + c8;
            *(bf16x8*)&Ks[krow * 64 + c8] = *(const bf16x8*)ksrc;
            const bf16* vsrc = qkv + base + (size_t)(kv0 + krow) * RS + 2 * E_ + h * HS_ + c8;
            bf16x8 vv = *(const bf16x8*)vsrc;
#pragma unroll
            for (int j = 0; j < 8; ++j) Vt[(c8 + j) * 64 + krow] = vv[j];
        }
        __syncthreads();
        // S = Q K^T  (S[q=4g+r][kv=16t+l15] per lane)
        f32x4 accS[4] = {};
#pragma unroll
        for (int t = 0; t < 4; ++t) {
#pragma unroll
            for (int kc = 0; kc < 2; ++kc) {
                bf16x8 kf = *(const bf16x8*)&Ks[(16 * t + l15) * 64 + kc * 32 + 8 * g];
                accS[t] = __builtin_amdgcn_mfma_f32_16x16x32_bf16(qf[kc], kf, accS[t], 0, 0, 0);
            }
        }
        float sarr[4][4];
        const bool diag = (kv0 == q0);
#pragma unroll
        for (int t = 0; t < 4; ++t)
#pragma unroll
            for (int r = 0; r < 4; ++r) {
                float s = accS[t][r] * 0.125f;   // HS^-0.5
                if (diag && (16 * t + l15 > 16 * wave + 4 * g + r)) s = -1e30f;
                sarr[t][r] = s;
            }
        float alpha[4];
#pragma unroll
        for (int r = 0; r < 4; ++r) {
            float mx = fmaxf(fmaxf(sarr[0][r], sarr[1][r]), fmaxf(sarr[2][r], sarr[3][r]));
#pragma unroll
            for (int m = 1; m < 16; m <<= 1) mx = fmaxf(mx, __shfl_xor(mx, m, 64));
            float mnew = fmaxf(mrow[r], mx);
            alpha[r] = __expf(mrow[r] - mnew);
            mrow[r] = mnew;
        }
#pragma unroll
        for (int t = 0; t < 4; ++t)
#pragma unroll
            for (int r = 0; r < 4; ++r) sarr[t][r] = __expf(sarr[t][r] - mrow[r]);
#pragma unroll
        for (int r = 0; r < 4; ++r) {
            float rs0 = sarr[0][r] + sarr[1][r] + sarr[2][r] + sarr[3][r];
#pragma unroll
            for (int m = 1; m < 16; m <<= 1) rs0 += __shfl_xor(rs0, m, 64);
            lrow[r] = lrow[r] * alpha[r] + rs0;
        }
#pragma unroll
        for (int u = 0; u < 4; ++u)
#pragma unroll
            for (int r = 0; r < 4; ++r) accO[u][r] *= alpha[r];
        // P -> LDS (per-wave private), then PV
#pragma unroll
        for (int t = 0; t < 4; ++t)
#pragma unroll
            for (int r = 0; r < 4; ++r)
                Ps[wave][(4 * g + r) * 64 + 16 * t + l15] = (bf16)sarr[t][r];
#pragma unroll
        for (int kc = 0; kc < 2; ++kc) {
            bf16x8 pf = *(const bf16x8*)&Ps[wave][l15 * 64 + kc * 32 + 8 * g];
#pragma unroll
            for (int u = 0; u < 4; ++u) {
                bf16x8 vf = *(const bf16x8*)&Vt[(16 * u + l15) * 64 + kc * 32 + 8 * g];
                accO[u] = __builtin_amdgcn_mfma_f32_16x16x32_bf16(pf, vf, accO[u], 0, 0, 0);
            }
        }
    }
#pragma unroll
    for (int u = 0; u < 4; ++u)
#pragma unroll
        for (int r = 0; r < 4; ++r) {
            int row = q0 + 16 * wave + 4 * g + r;
            out[((size_t)b * T_ + row) * E_ + h * HS_ + 16 * u + l15] =
                (bf16)(accO[u][r] / lrow[r]);
        }
}

// ---------------------------------------------------------------- out projection (fp32)
__global__ __launch_bounds__(256) void outproj_kernel(
    const float* __restrict__ hn, const float* __restrict__ W,
    const float* __restrict__ bias, float* __restrict__ out)
{
    int idx = blockIdx.x * 256 + threadIdx.x;   // M*16
    int row = idx >> 4, v = idx & 15;
    const float* hr = hn + (size_t)row * E_;
    float acc = 0.f;
#pragma unroll 8
    for (int k = 0; k < E_; ++k) acc += hr[k] * W[k * 16 + v];
    out[idx] = (acc + bias[v]) * 1.25f;   // 1/TEMP, TEMP=0.8
}

// ---------------------------------------------------------------- host
extern "C" void kernel_launch(void* const* d_in, const int* in_sizes, int n_in,
                              void* d_out, int out_size, void* d_ws, size_t ws_size,
                              hipStream_t stream)
{
    const int*   x      = (const int*)d_in[0];
    const float* emb    = (const float*)d_in[1];
    const float* pos    = (const float*)d_in[2];
    const float* wq     = (const float*)d_in[3];
    const float* wk     = (const float*)d_in[4];
    const float* wv     = (const float*)d_in[5];
    const float* proj_w = (const float*)d_in[6];
    const float* proj_b = (const float*)d_in[7];
    const float* ln1_g  = (const float*)d_in[8];
    const float* ln1_b  = (const float*)d_in[9];
    const float* ln2_g  = (const float*)d_in[10];
    const float* ln2_b  = (const float*)d_in[11];
    const float* ff_w1  = (const float*)d_in[12];
    const float* ff_b1  = (const float*)d_in[13];
    const float* ff_w2  = (const float*)d_in[14];
    const float* ff_b2  = (const float*)d_in[15];
    const float* lnf_g  = (const float*)d_in[16];
    const float* lnf_b  = (const float*)d_in[17];
    const float* out_w  = (const float*)d_in[18];
    const float* out_b  = (const float*)d_in[19];

    char* ws = (char*)d_ws;
    size_t off = 0;
    auto alloc = [&](size_t bytes) { size_t r = off; off += (bytes + 255) & ~(size_t)255; return r; };
    bf16*  wqkv_t = (bf16*)(ws + alloc((size_t)NB_ * 1536 * 512 * 2));
    bf16*  projt  = (bf16*)(ws + alloc((size_t)NB_ * 512 * 512 * 2));
    bf16*  ff1t   = (bf16*)(ws + alloc((size_t)NB_ * 2048 * 512 * 2));
    bf16*  ff2t   = (bf16*)(ws + alloc((size_t)NB_ * 512 * 2048 * 2));
    float* h      = (float*)(ws + alloc((size_t)M_ * 512 * 4));
    bf16*  xn     = (bf16*)(ws + alloc((size_t)M_ * 512 * 2));
    bf16*  qkvb   = (bf16*)(ws + alloc((size_t)M_ * 1536 * 2));
    bf16*  aout   = (bf16*)(ws + alloc((size_t)M_ * 512 * 2));
    bf16*  ffact  = (bf16*)(ws + alloc((size_t)M_ * 2048 * 2));
    float* hn     = (float*)(ws + alloc((size_t)M_ * 512 * 4));
    (void)ws_size; (void)in_sizes; (void)n_in; (void)out_size;

    // weight prep (tiled, coalesced)
    conv_qkv_tiled<<<dim3(16, 24, NB_), 256, 0, stream>>>(wq, wk, wv, wqkv_t);
    transpose_tiled<<<dim3(512 / 32, 512 / 32, NB_), 256, 0, stream>>>(proj_w, projt, 512, 512);
    transpose_tiled<<<dim3(2048 / 32, 512 / 32, NB_), 256, 0, stream>>>(ff_w1, ff1t, 512, 2048);
    transpose_tiled<<<dim3(512 / 32, 2048 / 32, NB_), 256, 0, stream>>>(ff_w2, ff2t, 2048, 512);

    embed_kernel<<<(M_ * 128) / 256, 256, 0, stream>>>(x, emb, pos, h);

    for (int i = 0; i < NB_; ++i) {
        ln_kernel<0><<<M_ / 4, 256, 0, stream>>>(h, ln1_g + i * 512, ln1_b + i * 512, xn);
        gemm_bt<0, 0, 0, 1><<<dim3(1536 / 128, M_ / 128), 256, 0, stream>>>(
            xn, wqkv_t + (size_t)i * 1536 * 512, nullptr, nullptr, qkvb, M_, 1536, 512);
        attn_kernel<<<dim3(T_ / 64, B_ * NH_), 256, 0, stream>>>(qkvb, aout);
        gemm_bt<1, 1, 0, 0><<<dim3(512 / 128, M_ / 128), 256, 0, stream>>>(
            aout, projt + (size_t)i * 512 * 512, proj_b + i * 512, h, h, M_, 512, 512);
        ln_kernel<0><<<M_ / 4, 256, 0, stream>>>(h, ln2_g + i * 512, ln2_b + i * 512, xn);
        gemm_bt<1, 0, 1, 1><<<dim3(2048 / 128, M_ / 128), 256, 0, stream>>>(
            xn, ff1t + (size_t)i * 2048 * 512, ff_b1 + i * 2048, nullptr, ffact, M_, 2048, 512);
        gemm_bt<1, 1, 0, 0><<<dim3(512 / 128, M_ / 128), 256, 0, stream>>>(
            ffact, ff2t + (size_t)i * 512 * 2048, ff_b2 + i * 512, h, h, M_, 512, 2048);
    }
    ln_kernel<1><<<M_ / 4, 256, 0, stream>>>(h, lnf_g, lnf_b, hn);
    outproj_kernel<<<(M_ * 16) / 256, 256, 0, stream>>>(hn, out_w, out_b, (float*)d_out);
}

// Round 7
// 1065.704 us; speedup vs baseline: 1.2683x; 1.2683x over previous
//
#include <hip/hip_runtime.h>
#include <hip/hip_bf16.h>

typedef __bf16 bf16;
typedef __bf16 bf16x8 __attribute__((ext_vector_type(8)));
typedef float f32x4 __attribute__((ext_vector_type(4)));

#define NB_ 6
#define E_ 512
#define NH_ 8
#define HS_ 64
#define FF_ 2048
#define B_ 16
#define T_ 512
#define M_ 8192   // B*T

// chunk swizzle: storage chunk = logical chunk ^ SW(row)  (chunks = 16B units)
#define SW(r) (((r) ^ ((r) >> 3)) & 7)

typedef const __attribute__((address_space(1))) void* gptr_t;
typedef __attribute__((address_space(3))) void* sptr_t;

// ---------------------------------------------------------------- weight prep
// wq/wk/wv [i][h][e][d] -> dst[i][c][e], c = which*512 + h*64 + d (bf16)
__global__ __launch_bounds__(256) void conv_qkv_tiled(
    const float* __restrict__ wq, const float* __restrict__ wk,
    const float* __restrict__ wv, bf16* __restrict__ dst)
{
    __shared__ float tile[32][65];          // [e][d], pad to 65
    const int e0 = blockIdx.x * 32;
    const int wh = blockIdx.y;              // 0..23
    const int which = wh >> 3, h = wh & 7;
    const int i = blockIdx.z;
    const float* src = (which == 0) ? wq : (which == 1) ? wk : wv;
    src += (((size_t)i * NH_ + h) * E_ + e0) * HS_;
    const int d = threadIdx.x & 63, er = threadIdx.x >> 6;    // 4 e-rows/pass
#pragma unroll
    for (int j = 0; j < 32; j += 4)
        tile[j + er][d] = src[(size_t)(j + er) * HS_ + d];
    __syncthreads();
    const int e = threadIdx.x & 31, dr = threadIdx.x >> 5;    // 8 d-rows/pass
    bf16* dbase = dst + (size_t)i * 1536 * E_ + ((size_t)which * 512 + h * 64) * E_ + e0;
#pragma unroll
    for (int j = 0; j < 64; j += 8)
        dbase[(size_t)(j + dr) * E_ + e] = (bf16)tile[e][j + dr];
}

// src[i][K][N] f32 -> dst[i][N][K] bf16 (tiled, coalesced both sides)
__global__ __launch_bounds__(256) void transpose_tiled(
    const float* __restrict__ src, bf16* __restrict__ dst, int K, int N)
{
    __shared__ float tile[32][33];
    const int n0 = blockIdx.x * 32, k0 = blockIdx.y * 32;
    const size_t sb = (size_t)blockIdx.z * K * N;
    const int lx = threadIdx.x & 31, ly = threadIdx.x >> 5;   // 8 rows/pass
#pragma unroll
    for (int j = 0; j < 32; j += 8)
        tile[j + ly][lx] = src[sb + (size_t)(k0 + j + ly) * N + n0 + lx];
    __syncthreads();
#pragma unroll
    for (int j = 0; j < 32; j += 8)
        dst[sb + (size_t)(n0 + j + ly) * K + k0 + lx] = (bf16)tile[lx][j + ly];
}

// ---------------------------------------------------------------- embed
__global__ __launch_bounds__(256) void embed_kernel(
    const int* __restrict__ x, const float* __restrict__ emb,
    const float* __restrict__ pos, float* __restrict__ h)
{
    int idx = blockIdx.x * 256 + threadIdx.x;   // per float4, M*128 total
    int row = idx >> 7;
    int e4 = (idx & 127) << 2;
    int tok = x[row];
    int t = row & (T_ - 1);
    float4 a = *(const float4*)&emb[(size_t)tok * E_ + e4];
    float4 c = *(const float4*)&pos[(size_t)t * E_ + e4];
    float4 o; o.x = a.x + c.x; o.y = a.y + c.y; o.z = a.z + c.z; o.w = a.w + c.w;
    *(float4*)&h[(size_t)row * E_ + e4] = o;
}

// ---------------------------------------------------------------- layernorm
template<int OUT_F32>
__global__ __launch_bounds__(256) void ln_kernel(
    const float* __restrict__ x, const float* __restrict__ gw,
    const float* __restrict__ bw, void* __restrict__ out)
{
    int wave = threadIdx.x >> 6, lane = threadIdx.x & 63;
    int row = blockIdx.x * 4 + wave;
    const float* xr = x + (size_t)row * E_;
    float4 v0 = *(const float4*)&xr[lane * 8];
    float4 v1 = *(const float4*)&xr[lane * 8 + 4];
    float vals[8] = {v0.x, v0.y, v0.z, v0.w, v1.x, v1.y, v1.z, v1.w};
    float s = 0.f, ss = 0.f;
#pragma unroll
    for (int j = 0; j < 8; ++j) { s += vals[j]; ss += vals[j] * vals[j]; }
#pragma unroll
    for (int m = 1; m < 64; m <<= 1) { s += __shfl_xor(s, m, 64); ss += __shfl_xor(ss, m, 64); }
    float mu = s * (1.f / E_);
    float var = ss * (1.f / E_) - mu * mu;
    float rs = rsqrtf(var + 1e-5f);
    int e0 = lane * 8;
    if (OUT_F32) {
        float* o = (float*)out + (size_t)row * E_ + e0;
#pragma unroll
        for (int j = 0; j < 8; ++j) o[j] = (vals[j] - mu) * rs * gw[e0 + j] + bw[e0 + j];
    } else {
        bf16x8 o;
#pragma unroll
        for (int j = 0; j < 8; ++j) o[j] = (bf16)((vals[j] - mu) * rs * gw[e0 + j] + bw[e0 + j]);
        *(bf16x8*)&((bf16*)out)[(size_t)row * E_ + e0] = o;
    }
}

// ---------------------------------------------------------------- GEMM (A[M][K] x Bt[N][K]^T)
// BK=64, pre-swizzled global source -> linear global_load_lds -> swizzled ds_read
template<int HAS_BIAS, int HAS_RES, int RELU, int OUT_BF16>
__global__ __launch_bounds__(256) void gemm_bt(
    const bf16* __restrict__ A, const bf16* __restrict__ Bt,
    const float* __restrict__ bias, const float* __restrict__ res,
    void* __restrict__ out, int M, int N, int K)
{
    constexpr int BM = 128, BN = 128, BK = 64;
    __shared__ bf16 As[BM * BK];
    __shared__ bf16 Bs[BN * BK];
    const int tid = threadIdx.x;
    const int wave = tid >> 6, lane = tid & 63;
    const int l15 = lane & 15, g = lane >> 4;
    const int n0 = blockIdx.x * BN, m0 = blockIdx.y * BM;
    const int wm = (wave >> 1) * 64, wn = (wave & 1) * 64;
    const int sr = tid >> 3, sc = tid & 7;   // staging: row base, chunk
    f32x4 acc[4][4] = {};
    for (int k0 = 0; k0 < K; k0 += BK) {
        __syncthreads();
#pragma unroll
        for (int p = 0; p < 4; ++p) {
            int row = p * 32 + sr;
            int cg = sc ^ SW(row);           // pre-swizzled source chunk
            __builtin_amdgcn_global_load_lds(
                (gptr_t)&A[(size_t)(m0 + row) * K + k0 + cg * 8],
                (sptr_t)&As[row * 64 + sc * 8], 16, 0, 0);
        }
#pragma unroll
        for (int p = 0; p < 4; ++p) {
            int row = p * 32 + sr;
            int cg = sc ^ SW(row);
            __builtin_amdgcn_global_load_lds(
                (gptr_t)&Bt[(size_t)(n0 + row) * K + k0 + cg * 8],
                (sptr_t)&Bs[row * 64 + sc * 8], 16, 0, 0);
        }
        __syncthreads();
#pragma unroll
        for (int kk = 0; kk < 2; ++kk) {
            bf16x8 af[4], bg[4];
#pragma unroll
            for (int mi = 0; mi < 4; ++mi) {
                int row = wm + 16 * mi + l15;
                af[mi] = *(const bf16x8*)&As[row * 64 + ((kk * 4 + g) ^ SW(row)) * 8];
            }
#pragma unroll
            for (int ni = 0; ni < 4; ++ni) {
                int row = wn + 16 * ni + l15;
                bg[ni] = *(const bf16x8*)&Bs[row * 64 + ((kk * 4 + g) ^ SW(row)) * 8];
            }
#pragma unroll
            for (int mi = 0; mi < 4; ++mi)
#pragma unroll
                for (int ni = 0; ni < 4; ++ni)
                    acc[mi][ni] = __builtin_amdgcn_mfma_f32_16x16x32_bf16(
                        af[mi], bg[ni], acc[mi][ni], 0, 0, 0);
        }
    }
    // epilogue: C/D layout col=lane&15, row=(lane>>4)*4+reg  [measured m89]
#pragma unroll
    for (int mi = 0; mi < 4; ++mi) {
#pragma unroll
        for (int ni = 0; ni < 4; ++ni) {
#pragma unroll
            for (int r = 0; r < 4; ++r) {
                int rr = m0 + wm + 16 * mi + 4 * g + r;
                int cc = n0 + wn + 16 * ni + l15;
                float v = acc[mi][ni][r];
                if (HAS_BIAS) v += bias[cc];
                if (HAS_RES) v += res[(size_t)rr * N + cc];
                if (RELU) v = fmaxf(v, 0.f);
                if (OUT_BF16) ((bf16*)out)[(size_t)rr * N + cc] = (bf16)v;
                else ((float*)out)[(size_t)rr * N + cc] = v;
            }
        }
    }
}

// ---------------------------------------------------------------- attention
// qkv: [B*T][1536] bf16 (q|k|v, col = h*64+d). out: [B*T][512] bf16.
// grid: (4 pairs, B*NH). block pair p handles q-tiles p and 7-p (9 tile-units).
__global__ __launch_bounds__(256) void attn_kernel(
    const bf16* __restrict__ qkv, bf16* __restrict__ out)
{
    constexpr int RS = 3 * E_;   // 1536 row stride
    __shared__ bf16 Ks[64 * 64];
    __shared__ bf16 Vt[64 * 64];
    __shared__ bf16 Ps[4][16 * 64];
    const int tid = threadIdx.x;
    const int wave = tid >> 6, lane = tid & 63;
    const int l15 = lane & 15, g = lane >> 4;
    const int bh = blockIdx.y;
    const int b = bh >> 3, h = bh & 7;
    const size_t base = (size_t)b * T_ * RS;
    const bf16* kb = qkv + base + E_ + h * HS_;
    const bf16* vb = qkv + base + 2 * E_ + h * HS_;
    const int strow = tid >> 3, stc = tid & 7;   // staging row/chunk

    for (int half = 0; half < 2; ++half) {
        const int qt = half == 0 ? (int)blockIdx.x : 7 - (int)blockIdx.x;
        const int q0 = qt * 64;
        const int ntiles = qt + 1;
        bf16x8 qf[2];
        {
            const bf16* qrow = qkv + base + (size_t)(q0 + wave * 16 + l15) * RS + h * HS_;
            qf[0] = *(const bf16x8*)&qrow[8 * g];
            qf[1] = *(const bf16x8*)&qrow[32 + 8 * g];
        }
        float mrow[4] = {-1e30f, -1e30f, -1e30f, -1e30f};
        float lrow[4] = {0.f, 0.f, 0.f, 0.f};
        f32x4 accO[4] = {};
        // prefetch tile 0 into regs
        bf16x8 kreg[2], vreg[2];
#pragma unroll
        for (int r = 0; r < 2; ++r) {
            int krow = r * 32 + strow;
            kreg[r] = *(const bf16x8*)&kb[(size_t)krow * RS + stc * 8];
            vreg[r] = *(const bf16x8*)&vb[(size_t)krow * RS + stc * 8];
        }
        for (int tile = 0; tile < ntiles; ++tile) {
            __syncthreads();   // previous compute done, LDS free
            // write staged regs -> LDS (swizzled)
#pragma unroll
            for (int r = 0; r < 2; ++r) {
                int krow = r * 32 + strow;
                *(bf16x8*)&Ks[krow * 64 + (stc ^ SW(krow)) * 8] = kreg[r];
#pragma unroll
                for (int j = 0; j < 8; ++j) {
                    int drow = stc * 8 + j;
                    Vt[drow * 64 + ((krow >> 3) ^ SW(drow)) * 8 + (krow & 7)] = vreg[r][j];
                }
            }
            // prefetch next tile (overlaps with compute below)
            if (tile + 1 < ntiles) {
                int kv = (tile + 1) * 64;
#pragma unroll
                for (int r = 0; r < 2; ++r) {
                    int krow = kv + r * 32 + strow;
                    kreg[r] = *(const bf16x8*)&kb[(size_t)krow * RS + stc * 8];
                    vreg[r] = *(const bf16x8*)&vb[(size_t)krow * RS + stc * 8];
                }
            }
            __syncthreads();
            // S = Q K^T  (S[q=4g+r][kv=16t+l15] per lane)
            f32x4 accS[4] = {};
#pragma unroll
            for (int t = 0; t < 4; ++t) {
                int rk = 16 * t + l15;
#pragma unroll
                for (int kc = 0; kc < 2; ++kc) {
                    bf16x8 kf = *(const bf16x8*)&Ks[rk * 64 + ((kc * 4 + g) ^ SW(rk)) * 8];
                    accS[t] = __builtin_amdgcn_mfma_f32_16x16x32_bf16(qf[kc], kf, accS[t], 0, 0, 0);
                }
            }
            float sarr[4][4];
            const bool diag = (tile == qt);
#pragma unroll
            for (int t = 0; t < 4; ++t)
#pragma unroll
                for (int r = 0; r < 4; ++r) {
                    float s = accS[t][r] * 0.125f;   // HS^-0.5
                    if (diag && (16 * t + l15 > 16 * wave + 4 * g + r)) s = -1e30f;
                    sarr[t][r] = s;
                }
            float alpha[4];
#pragma unroll
            for (int r = 0; r < 4; ++r) {
                float mx = fmaxf(fmaxf(sarr[0][r], sarr[1][r]), fmaxf(sarr[2][r], sarr[3][r]));
#pragma unroll
                for (int m = 1; m < 16; m <<= 1) mx = fmaxf(mx, __shfl_xor(mx, m, 64));
                float mnew = fmaxf(mrow[r], mx);
                alpha[r] = __expf(mrow[r] - mnew);
                mrow[r] = mnew;
            }
#pragma unroll
            for (int t = 0; t < 4; ++t)
#pragma unroll
                for (int r = 0; r < 4; ++r) sarr[t][r] = __expf(sarr[t][r] - mrow[r]);
#pragma unroll
            for (int r = 0; r < 4; ++r) {
                float rs0 = sarr[0][r] + sarr[1][r] + sarr[2][r] + sarr[3][r];
#pragma unroll
                for (int m = 1; m < 16; m <<= 1) rs0 += __shfl_xor(rs0, m, 64);
                lrow[r] = lrow[r] * alpha[r] + rs0;
            }
#pragma unroll
            for (int u = 0; u < 4; ++u)
#pragma unroll
                for (int r = 0; r < 4; ++r) accO[u][r] *= alpha[r];
            // P -> LDS (wave-private, swizzled), then PV
#pragma unroll
            for (int t = 0; t < 4; ++t)
#pragma unroll
                for (int r = 0; r < 4; ++r) {
                    int prow = 4 * g + r;
                    Ps[wave][prow * 64 + ((2 * t + (l15 >> 3)) ^ SW(prow)) * 8 + (l15 & 7)] =
                        (bf16)sarr[t][r];
                }
#pragma unroll
            for (int kc = 0; kc < 2; ++kc) {
                bf16x8 pf = *(const bf16x8*)&Ps[wave][l15 * 64 + ((kc * 4 + g) ^ SW(l15)) * 8];
#pragma unroll
                for (int u = 0; u < 4; ++u) {
                    int rv = 16 * u + l15;
                    bf16x8 vf = *(const bf16x8*)&Vt[rv * 64 + ((kc * 4 + g) ^ SW(rv)) * 8];
                    accO[u] = __builtin_amdgcn_mfma_f32_16x16x32_bf16(pf, vf, accO[u], 0, 0, 0);
                }
            }
        }
#pragma unroll
        for (int u = 0; u < 4; ++u)
#pragma unroll
            for (int r = 0; r < 4; ++r) {
                int row = q0 + 16 * wave + 4 * g + r;
                out[((size_t)b * T_ + row) * E_ + h * HS_ + 16 * u + l15] =
                    (bf16)(accO[u][r] / lrow[r]);
            }
    }
}

// ---------------------------------------------------------------- out projection (fp32)
__global__ __launch_bounds__(256) void outproj_kernel(
    const float* __restrict__ hn, const float* __restrict__ W,
    const float* __restrict__ bias, float* __restrict__ out)
{
    int idx = blockIdx.x * 256 + threadIdx.x;   // M*16
    int row = idx >> 4, v = idx & 15;
    const float* hr = hn + (size_t)row * E_;
    float acc = 0.f;
#pragma unroll 8
    for (int k = 0; k < E_; ++k) acc += hr[k] * W[k * 16 + v];
    out[idx] = (acc + bias[v]) * 1.25f;   // 1/TEMP, TEMP=0.8
}

// ---------------------------------------------------------------- host
extern "C" void kernel_launch(void* const* d_in, const int* in_sizes, int n_in,
                              void* d_out, int out_size, void* d_ws, size_t ws_size,
                              hipStream_t stream)
{
    const int*   x      = (const int*)d_in[0];
    const float* emb    = (const float*)d_in[1];
    const float* pos    = (const float*)d_in[2];
    const float* wq     = (const float*)d_in[3];
    const float* wk     = (const float*)d_in[4];
    const float* wv     = (const float*)d_in[5];
    const float* proj_w = (const float*)d_in[6];
    const float* proj_b = (const float*)d_in[7];
    const float* ln1_g  = (const float*)d_in[8];
    const float* ln1_b  = (const float*)d_in[9];
    const float* ln2_g  = (const float*)d_in[10];
    const float* ln2_b  = (const float*)d_in[11];
    const float* ff_w1  = (const float*)d_in[12];
    const float* ff_b1  = (const float*)d_in[13];
    const float* ff_w2  = (const float*)d_in[14];
    const float* ff_b2  = (const float*)d_in[15];
    const float* lnf_g  = (const float*)d_in[16];
    const float* lnf_b  = (const float*)d_in[17];
    const float* out_w  = (const float*)d_in[18];
    const float* out_b  = (const float*)d_in[19];

    char* ws = (char*)d_ws;
    size_t off = 0;
    auto alloc = [&](size_t bytes) { size_t r = off; off += (bytes + 255) & ~(size_t)255; return r; };
    bf16*  wqkv_t = (bf16*)(ws + alloc((size_t)NB_ * 1536 * 512 * 2));
    bf16*  projt  = (bf16*)(ws + alloc((size_t)NB_ * 512 * 512 * 2));
    bf16*  ff1t   = (bf16*)(ws + alloc((size_t)NB_ * 2048 * 512 * 2));
    bf16*  ff2t   = (bf16*)(ws + alloc((size_t)NB_ * 512 * 2048 * 2));
    float* h      = (float*)(ws + alloc((size_t)M_ * 512 * 4));
    bf16*  xn     = (bf16*)(ws + alloc((size_t)M_ * 512 * 2));
    bf16*  qkvb   = (bf16*)(ws + alloc((size_t)M_ * 1536 * 2));
    bf16*  aout   = (bf16*)(ws + alloc((size_t)M_ * 512 * 2));
    bf16*  ffact  = (bf16*)(ws + alloc((size_t)M_ * 2048 * 2));
    float* hn     = (float*)(ws + alloc((size_t)M_ * 512 * 4));
    (void)ws_size; (void)in_sizes; (void)n_in; (void)out_size;

    // weight prep (tiled, coalesced)
    conv_qkv_tiled<<<dim3(16, 24, NB_), 256, 0, stream>>>(wq, wk, wv, wqkv_t);
    transpose_tiled<<<dim3(512 / 32, 512 / 32, NB_), 256, 0, stream>>>(proj_w, projt, 512, 512);
    transpose_tiled<<<dim3(2048 / 32, 512 / 32, NB_), 256, 0, stream>>>(ff_w1, ff1t, 512, 2048);
    transpose_tiled<<<dim3(512 / 32, 2048 / 32, NB_), 256, 0, stream>>>(ff_w2, ff2t, 2048, 512);

    embed_kernel<<<(M_ * 128) / 256, 256, 0, stream>>>(x, emb, pos, h);

    for (int i = 0; i < NB_; ++i) {
        ln_kernel<0><<<M_ / 4, 256, 0, stream>>>(h, ln1_g + i * 512, ln1_b + i * 512, xn);
        gemm_bt<0, 0, 0, 1><<<dim3(1536 / 128, M_ / 128), 256, 0, stream>>>(
            xn, wqkv_t + (size_t)i * 1536 * 512, nullptr, nullptr, qkvb, M_, 1536, 512);
        attn_kernel<<<dim3(4, B_ * NH_), 256, 0, stream>>>(qkvb, aout);
        gemm_bt<1, 1, 0, 0><<<dim3(512 / 128, M_ / 128), 256, 0, stream>>>(
            aout, projt + (size_t)i * 512 * 512, proj_b + i * 512, h, h, M_, 512, 512);
        ln_kernel<0><<<M_ / 4, 256, 0, stream>>>(h, ln2_g + i * 512, ln2_b + i * 512, xn);
        gemm_bt<1, 0, 1, 1><<<dim3(2048 / 128, M_ / 128), 256, 0, stream>>>(
            xn, ff1t + (size_t)i * 2048 * 512, ff_b1 + i * 2048, nullptr, ffact, M_, 2048, 512);
        gemm_bt<1, 1, 0, 0><<<dim3(512 / 128, M_ / 128), 256, 0, stream>>>(
            ffact, ff2t + (size_t)i * 512 * 2048, ff_b2 + i * 512, h, h, M_, 512, 2048);
    }
    ln_kernel<1><<<M_ / 4, 256, 0, stream>>>(h, lnf_g, lnf_b, hn);
    outproj_kernel<<<(M_ * 16) / 256, 256, 0, stream>>>(hn, out_w, out_b, (float*)d_out);
}

// Round 8
// 1028.505 us; speedup vs baseline: 1.3142x; 1.0362x over previous
//
#include <hip/hip_runtime.h>
#include <hip/hip_bf16.h>

typedef __bf16 bf16;
typedef __bf16 bf16x8 __attribute__((ext_vector_type(8)));
typedef float f32x4 __attribute__((ext_vector_type(4)));

#define NB_ 6
#define E_ 512
#define NH_ 8
#define HS_ 64
#define FF_ 2048
#define B_ 16
#define T_ 512
#define M_ 8192   // B*T

// chunk swizzle: storage chunk = logical chunk ^ SW(row)  (chunks = 16B units)
#define SW(r) (((r) ^ ((r) >> 3)) & 7)

typedef const __attribute__((address_space(1))) void* gptr_t;
typedef __attribute__((address_space(3))) void* sptr_t;

// ---------------------------------------------------------------- weight prep
// wq/wk/wv [i][h][e][d] -> dst[i][c][e], c = which*512 + h*64 + d (bf16)
__global__ __launch_bounds__(256) void conv_qkv_tiled(
    const float* __restrict__ wq, const float* __restrict__ wk,
    const float* __restrict__ wv, bf16* __restrict__ dst)
{
    __shared__ float tile[32][65];          // [e][d], pad to 65
    const int e0 = blockIdx.x * 32;
    const int wh = blockIdx.y;              // 0..23
    const int which = wh >> 3, h = wh & 7;
    const int i = blockIdx.z;
    const float* src = (which == 0) ? wq : (which == 1) ? wk : wv;
    src += (((size_t)i * NH_ + h) * E_ + e0) * HS_;
    const int d = threadIdx.x & 63, er = threadIdx.x >> 6;    // 4 e-rows/pass
#pragma unroll
    for (int j = 0; j < 32; j += 4)
        tile[j + er][d] = src[(size_t)(j + er) * HS_ + d];
    __syncthreads();
    const int e = threadIdx.x & 31, dr = threadIdx.x >> 5;    // 8 d-rows/pass
    bf16* dbase = dst + (size_t)i * 1536 * E_ + ((size_t)which * 512 + h * 64) * E_ + e0;
#pragma unroll
    for (int j = 0; j < 64; j += 8)
        dbase[(size_t)(j + dr) * E_ + e] = (bf16)tile[e][j + dr];
}

// src[i][K][N] f32 -> dst[i][N][K] bf16 (tiled, coalesced both sides)
__global__ __launch_bounds__(256) void transpose_tiled(
    const float* __restrict__ src, bf16* __restrict__ dst, int K, int N)
{
    __shared__ float tile[32][33];
    const int n0 = blockIdx.x * 32, k0 = blockIdx.y * 32;
    const size_t sb = (size_t)blockIdx.z * K * N;
    const int lx = threadIdx.x & 31, ly = threadIdx.x >> 5;   // 8 rows/pass
#pragma unroll
    for (int j = 0; j < 32; j += 8)
        tile[j + ly][lx] = src[sb + (size_t)(k0 + j + ly) * N + n0 + lx];
    __syncthreads();
#pragma unroll
    for (int j = 0; j < 32; j += 8)
        dst[sb + (size_t)(n0 + j + ly) * K + k0 + lx] = (bf16)tile[lx][j + ly];
}

// ---------------------------------------------------------------- embed
__global__ __launch_bounds__(256) void embed_kernel(
    const int* __restrict__ x, const float* __restrict__ emb,
    const float* __restrict__ pos, float* __restrict__ h)
{
    int idx = blockIdx.x * 256 + threadIdx.x;   // per float4, M*128 total
    int row = idx >> 7;
    int e4 = (idx & 127) << 2;
    int tok = x[row];
    int t = row & (T_ - 1);
    float4 a = *(const float4*)&emb[(size_t)tok * E_ + e4];
    float4 c = *(const float4*)&pos[(size_t)t * E_ + e4];
    float4 o; o.x = a.x + c.x; o.y = a.y + c.y; o.z = a.z + c.z; o.w = a.w + c.w;
    *(float4*)&h[(size_t)row * E_ + e4] = o;
}

// ---------------------------------------------------------------- layernorm
template<int OUT_F32>
__global__ __launch_bounds__(256) void ln_kernel(
    const float* __restrict__ x, const float* __restrict__ gw,
    const float* __restrict__ bw, void* __restrict__ out)
{
    int wave = threadIdx.x >> 6, lane = threadIdx.x & 63;
    int row = blockIdx.x * 4 + wave;
    const float* xr = x + (size_t)row * E_;
    float4 v0 = *(const float4*)&xr[lane * 8];
    float4 v1 = *(const float4*)&xr[lane * 8 + 4];
    float vals[8] = {v0.x, v0.y, v0.z, v0.w, v1.x, v1.y, v1.z, v1.w};
    float s = 0.f, ss = 0.f;
#pragma unroll
    for (int j = 0; j < 8; ++j) { s += vals[j]; ss += vals[j] * vals[j]; }
#pragma unroll
    for (int m = 1; m < 64; m <<= 1) { s += __shfl_xor(s, m, 64); ss += __shfl_xor(ss, m, 64); }
    float mu = s * (1.f / E_);
    float var = ss * (1.f / E_) - mu * mu;
    float rs = rsqrtf(var + 1e-5f);
    int e0 = lane * 8;
    if (OUT_F32) {
        float* o = (float*)out + (size_t)row * E_ + e0;
#pragma unroll
        for (int j = 0; j < 8; ++j) o[j] = (vals[j] - mu) * rs * gw[e0 + j] + bw[e0 + j];
    } else {
        bf16x8 o;
#pragma unroll
        for (int j = 0; j < 8; ++j) o[j] = (bf16)((vals[j] - mu) * rs * gw[e0 + j] + bw[e0 + j]);
        *(bf16x8*)&((bf16*)out)[(size_t)row * E_ + e0] = o;
    }
}

// ---------------------------------------------------------------- GEMM (A[M][K] x Bt[N][K]^T)
// BM=128, BN templated (128 or 64) so small-N GEMMs get >=2 blocks/CU.
// BK=64, pre-swizzled global source -> linear global_load_lds -> swizzled ds_read
template<int BN_T, int HAS_BIAS, int HAS_RES, int RELU, int OUT_BF16>
__global__ __launch_bounds__(256) void gemm_bt(
    const bf16* __restrict__ A, const bf16* __restrict__ Bt,
    const float* __restrict__ bias, const float* __restrict__ res,
    void* __restrict__ out, int M, int N, int K)
{
    constexpr int BM = 128, BK = 64;
    constexpr int NI = BN_T / 32;          // n-frags per wave (wave n-tile = BN_T/2)
    __shared__ bf16 As[BM * BK];
    __shared__ bf16 Bs[BN_T * BK];
    const int tid = threadIdx.x;
    const int wave = tid >> 6, lane = tid & 63;
    const int l15 = lane & 15, g = lane >> 4;
    const int n0 = blockIdx.x * BN_T, m0 = blockIdx.y * BM;
    const int wm = (wave >> 1) * 64, wn = (wave & 1) * (BN_T / 2);
    const int sr = tid >> 3, sc = tid & 7;   // staging: row base, chunk
    f32x4 acc[4][NI] = {};
    for (int k0 = 0; k0 < K; k0 += BK) {
        __syncthreads();
#pragma unroll
        for (int p = 0; p < 4; ++p) {
            int row = p * 32 + sr;
            int cg = sc ^ SW(row);           // pre-swizzled source chunk
            __builtin_amdgcn_global_load_lds(
                (gptr_t)&A[(size_t)(m0 + row) * K + k0 + cg * 8],
                (sptr_t)&As[row * 64 + sc * 8], 16, 0, 0);
        }
#pragma unroll
        for (int p = 0; p < BN_T / 32; ++p) {
            int row = p * 32 + sr;
            int cg = sc ^ SW(row);
            __builtin_amdgcn_global_load_lds(
                (gptr_t)&Bt[(size_t)(n0 + row) * K + k0 + cg * 8],
                (sptr_t)&Bs[row * 64 + sc * 8], 16, 0, 0);
        }
        __syncthreads();
#pragma unroll
        for (int kk = 0; kk < 2; ++kk) {
            bf16x8 af[4], bg[NI];
#pragma unroll
            for (int mi = 0; mi < 4; ++mi) {
                int row = wm + 16 * mi + l15;
                af[mi] = *(const bf16x8*)&As[row * 64 + ((kk * 4 + g) ^ SW(row)) * 8];
            }
#pragma unroll
            for (int ni = 0; ni < NI; ++ni) {
                int row = wn + 16 * ni + l15;
                bg[ni] = *(const bf16x8*)&Bs[row * 64 + ((kk * 4 + g) ^ SW(row)) * 8];
            }
#pragma unroll
            for (int mi = 0; mi < 4; ++mi)
#pragma unroll
                for (int ni = 0; ni < NI; ++ni)
                    acc[mi][ni] = __builtin_amdgcn_mfma_f32_16x16x32_bf16(
                        af[mi], bg[ni], acc[mi][ni], 0, 0, 0);
        }
    }
    // epilogue: C/D layout col=lane&15, row=(lane>>4)*4+reg  [measured m89]
#pragma unroll
    for (int mi = 0; mi < 4; ++mi) {
#pragma unroll
        for (int ni = 0; ni < NI; ++ni) {
#pragma unroll
            for (int r = 0; r < 4; ++r) {
                int rr = m0 + wm + 16 * mi + 4 * g + r;
                int cc = n0 + wn + 16 * ni + l15;
                float v = acc[mi][ni][r];
                if (HAS_BIAS) v += bias[cc];
                if (HAS_RES) v += res[(size_t)rr * N + cc];
                if (RELU) v = fmaxf(v, 0.f);
                if (OUT_BF16) ((bf16*)out)[(size_t)rr * N + cc] = (bf16)v;
                else ((float*)out)[(size_t)rr * N + cc] = v;
            }
        }
    }
}

// ---------------------------------------------------------------- attention
// qkv: [B*T][1536] bf16 (q|k|v, col = h*64+d). out: [B*T][512] bf16.
// grid: (4 pairs, B*NH). block pair p handles q-tiles p and 7-p (9 tile-units).
__global__ __launch_bounds__(256) void attn_kernel(
    const bf16* __restrict__ qkv, bf16* __restrict__ out)
{
    constexpr int RS = 3 * E_;   // 1536 row stride
    __shared__ bf16 Ks[64 * 64];
    __shared__ bf16 Vt[64 * 64];
    __shared__ bf16 Ps[4][16 * 64];
    const int tid = threadIdx.x;
    const int wave = tid >> 6, lane = tid & 63;
    const int l15 = lane & 15, g = lane >> 4;
    const int bh = blockIdx.y;
    const int b = bh >> 3, h = bh & 7;
    const size_t base = (size_t)b * T_ * RS;
    const bf16* kb = qkv + base + E_ + h * HS_;
    const bf16* vb = qkv + base + 2 * E_ + h * HS_;
    const int strow = tid >> 3, stc = tid & 7;   // staging row/chunk

    for (int half = 0; half < 2; ++half) {
        const int qt = half == 0 ? (int)blockIdx.x : 7 - (int)blockIdx.x;
        const int q0 = qt * 64;
        const int ntiles = qt + 1;
        bf16x8 qf[2];
        {
            const bf16* qrow = qkv + base + (size_t)(q0 + wave * 16 + l15) * RS + h * HS_;
            qf[0] = *(const bf16x8*)&qrow[8 * g];
            qf[1] = *(const bf16x8*)&qrow[32 + 8 * g];
        }
        float mrow[4] = {-1e30f, -1e30f, -1e30f, -1e30f};
        float lrow[4] = {0.f, 0.f, 0.f, 0.f};
        f32x4 accO[4] = {};
        // prefetch tile 0 into regs
        bf16x8 kreg[2], vreg[2];
#pragma unroll
        for (int r = 0; r < 2; ++r) {
            int krow = r * 32 + strow;
            kreg[r] = *(const bf16x8*)&kb[(size_t)krow * RS + stc * 8];
            vreg[r] = *(const bf16x8*)&vb[(size_t)krow * RS + stc * 8];
        }
        for (int tile = 0; tile < ntiles; ++tile) {
            __syncthreads();   // previous compute done, LDS free
            // write staged regs -> LDS (swizzled)
#pragma unroll
            for (int r = 0; r < 2; ++r) {
                int krow = r * 32 + strow;
                *(bf16x8*)&Ks[krow * 64 + (stc ^ SW(krow)) * 8] = kreg[r];
#pragma unroll
                for (int j = 0; j < 8; ++j) {
                    int drow = stc * 8 + j;
                    Vt[drow * 64 + ((krow >> 3) ^ SW(drow)) * 8 + (krow & 7)] = vreg[r][j];
                }
            }
            // prefetch next tile (overlaps with compute below)
            if (tile + 1 < ntiles) {
                int kv = (tile + 1) * 64;
#pragma unroll
                for (int r = 0; r < 2; ++r) {
                    int krow = kv + r * 32 + strow;
                    kreg[r] = *(const bf16x8*)&kb[(size_t)krow * RS + stc * 8];
                    vreg[r] = *(const bf16x8*)&vb[(size_t)krow * RS + stc * 8];
                }
            }
            __syncthreads();
            // S = Q K^T  (S[q=4g+r][kv=16t+l15] per lane)
            f32x4 accS[4] = {};
#pragma unroll
            for (int t = 0; t < 4; ++t) {
                int rk = 16 * t + l15;
#pragma unroll
                for (int kc = 0; kc < 2; ++kc) {
                    bf16x8 kf = *(const bf16x8*)&Ks[rk * 64 + ((kc * 4 + g) ^ SW(rk)) * 8];
                    accS[t] = __builtin_amdgcn_mfma_f32_16x16x32_bf16(qf[kc], kf, accS[t], 0, 0, 0);
                }
            }
            float sarr[4][4];
            const bool diag = (tile == qt);
#pragma unroll
            for (int t = 0; t < 4; ++t)
#pragma unroll
                for (int r = 0; r < 4; ++r) {
                    float s = accS[t][r] * 0.125f;   // HS^-0.5
                    if (diag && (16 * t + l15 > 16 * wave + 4 * g + r)) s = -1e30f;
                    sarr[t][r] = s;
                }
            float alpha[4];
#pragma unroll
            for (int r = 0; r < 4; ++r) {
                float mx = fmaxf(fmaxf(sarr[0][r], sarr[1][r]), fmaxf(sarr[2][r], sarr[3][r]));
#pragma unroll
                for (int m = 1; m < 16; m <<= 1) mx = fmaxf(mx, __shfl_xor(mx, m, 64));
                float mnew = fmaxf(mrow[r], mx);
                alpha[r] = __expf(mrow[r] - mnew);
                mrow[r] = mnew;
            }
#pragma unroll
            for (int t = 0; t < 4; ++t)
#pragma unroll
                for (int r = 0; r < 4; ++r) sarr[t][r] = __expf(sarr[t][r] - mrow[r]);
#pragma unroll
            for (int r = 0; r < 4; ++r) {
                float rs0 = sarr[0][r] + sarr[1][r] + sarr[2][r] + sarr[3][r];
#pragma unroll
                for (int m = 1; m < 16; m <<= 1) rs0 += __shfl_xor(rs0, m, 64);
                lrow[r] = lrow[r] * alpha[r] + rs0;
            }
#pragma unroll
            for (int u = 0; u < 4; ++u)
#pragma unroll
                for (int r = 0; r < 4; ++r) accO[u][r] *= alpha[r];
            // P -> LDS (wave-private, swizzled), then PV
#pragma unroll
            for (int t = 0; t < 4; ++t)
#pragma unroll
                for (int r = 0; r < 4; ++r) {
                    int prow = 4 * g + r;
                    Ps[wave][prow * 64 + ((2 * t + (l15 >> 3)) ^ SW(prow)) * 8 + (l15 & 7)] =
                        (bf16)sarr[t][r];
                }
#pragma unroll
            for (int kc = 0; kc < 2; ++kc) {
                bf16x8 pf = *(const bf16x8*)&Ps[wave][l15 * 64 + ((kc * 4 + g) ^ SW(l15)) * 8];
#pragma unroll
                for (int u = 0; u < 4; ++u) {
                    int rv = 16 * u + l15;
                    bf16x8 vf = *(const bf16x8*)&Vt[rv * 64 + ((kc * 4 + g) ^ SW(rv)) * 8];
                    accO[u] = __builtin_amdgcn_mfma_f32_16x16x32_bf16(pf, vf, accO[u], 0, 0, 0);
                }
            }
        }
#pragma unroll
        for (int u = 0; u < 4; ++u)
#pragma unroll
            for (int r = 0; r < 4; ++r) {
                int row = q0 + 16 * wave + 4 * g + r;
                out[((size_t)b * T_ + row) * E_ + h * HS_ + 16 * u + l15] =
                    (bf16)(accO[u][r] / lrow[r]);
            }
    }
}

// ---------------------------------------------------------------- out projection (fp32)
__global__ __launch_bounds__(256) void outproj_kernel(
    const float* __restrict__ hn, const float* __restrict__ W,
    const float* __restrict__ bias, float* __restrict__ out)
{
    int idx = blockIdx.x * 256 + threadIdx.x;   // M*16
    int row = idx >> 4, v = idx & 15;
    const float* hr = hn + (size_t)row * E_;
    float acc = 0.f;
#pragma unroll 8
    for (int k = 0; k < E_; ++k) acc += hr[k] * W[k * 16 + v];
    out[idx] = (acc + bias[v]) * 1.25f;   // 1/TEMP, TEMP=0.8
}

// ---------------------------------------------------------------- host
extern "C" void kernel_launch(void* const* d_in, const int* in_sizes, int n_in,
                              void* d_out, int out_size, void* d_ws, size_t ws_size,
                              hipStream_t stream)
{
    const int*   x      = (const int*)d_in[0];
    const float* emb    = (const float*)d_in[1];
    const float* pos    = (const float*)d_in[2];
    const float* wq     = (const float*)d_in[3];
    const float* wk     = (const float*)d_in[4];
    const float* wv     = (const float*)d_in[5];
    const float* proj_w = (const float*)d_in[6];
    const float* proj_b = (const float*)d_in[7];
    const float* ln1_g  = (const float*)d_in[8];
    const float* ln1_b  = (const float*)d_in[9];
    const float* ln2_g  = (const float*)d_in[10];
    const float* ln2_b  = (const float*)d_in[11];
    const float* ff_w1  = (const float*)d_in[12];
    const float* ff_b1  = (const float*)d_in[13];
    const float* ff_w2  = (const float*)d_in[14];
    const float* ff_b2  = (const float*)d_in[15];
    const float* lnf_g  = (const float*)d_in[16];
    const float* lnf_b  = (const float*)d_in[17];
    const float* out_w  = (const float*)d_in[18];
    const float* out_b  = (const float*)d_in[19];

    char* ws = (char*)d_ws;
    size_t off = 0;
    auto alloc = [&](size_t bytes) { size_t r = off; off += (bytes + 255) & ~(size_t)255; return r; };
    bf16*  wqkv_t = (bf16*)(ws + alloc((size_t)NB_ * 1536 * 512 * 2));
    bf16*  projt  = (bf16*)(ws + alloc((size_t)NB_ * 512 * 512 * 2));
    bf16*  ff1t   = (bf16*)(ws + alloc((size_t)NB_ * 2048 * 512 * 2));
    bf16*  ff2t   = (bf16*)(ws + alloc((size_t)NB_ * 512 * 2048 * 2));
    float* h      = (float*)(ws + alloc((size_t)M_ * 512 * 4));
    bf16*  xn     = (bf16*)(ws + alloc((size_t)M_ * 512 * 2));
    bf16*  qkvb   = (bf16*)(ws + alloc((size_t)M_ * 1536 * 2));
    bf16*  aout   = (bf16*)(ws + alloc((size_t)M_ * 512 * 2));
    bf16*  ffact  = (bf16*)(ws + alloc((size_t)M_ * 2048 * 2));
    float* hn     = (float*)(ws + alloc((size_t)M_ * 512 * 4));
    (void)ws_size; (void)in_sizes; (void)n_in; (void)out_size;

    // weight prep (tiled, coalesced)
    conv_qkv_tiled<<<dim3(16, 24, NB_), 256, 0, stream>>>(wq, wk, wv, wqkv_t);
    transpose_tiled<<<dim3(512 / 32, 512 / 32, NB_), 256, 0, stream>>>(proj_w, projt, 512, 512);
    transpose_tiled<<<dim3(2048 / 32, 512 / 32, NB_), 256, 0, stream>>>(ff_w1, ff1t, 512, 2048);
    transpose_tiled<<<dim3(512 / 32, 2048 / 32, NB_), 256, 0, stream>>>(ff_w2, ff2t, 2048, 512);

    embed_kernel<<<(M_ * 128) / 256, 256, 0, stream>>>(x, emb, pos, h);

    for (int i = 0; i < NB_; ++i) {
        ln_kernel<0><<<M_ / 4, 256, 0, stream>>>(h, ln1_g + i * 512, ln1_b + i * 512, xn);
        gemm_bt<128, 0, 0, 0, 1><<<dim3(1536 / 128, M_ / 128), 256, 0, stream>>>(
            xn, wqkv_t + (size_t)i * 1536 * 512, nullptr, nullptr, qkvb, M_, 1536, 512);
        attn_kernel<<<dim3(4, B_ * NH_), 256, 0, stream>>>(qkvb, aout);
        gemm_bt<64, 1, 1, 0, 0><<<dim3(512 / 64, M_ / 128), 256, 0, stream>>>(
            aout, projt + (size_t)i * 512 * 512, proj_b + i * 512, h, h, M_, 512, 512);
        ln_kernel<0><<<M_ / 4, 256, 0, stream>>>(h, ln2_g + i * 512, ln2_b + i * 512, xn);
        gemm_bt<128, 1, 0, 1, 1><<<dim3(2048 / 128, M_ / 128), 256, 0, stream>>>(
            xn, ff1t + (size_t)i * 2048 * 512, ff_b1 + i * 2048, nullptr, ffact, M_, 2048, 512);
        gemm_bt<64, 1, 1, 0, 0><<<dim3(512 / 64, M_ / 128), 256, 0, stream>>>(
            ffact, ff2t + (size_t)i * 512 * 2048, ff_b2 + i * 512, h, h, M_, 512, 2048);
    }
    ln_kernel<1><<<M_ / 4, 256, 0, stream>>>(h, lnf_g, lnf_b, hn);
    outproj_kernel<<<(M_ * 16) / 256, 256, 0, stream>>>(hn, out_w, out_b, (float*)d_out);
}

// Round 9
// 937.134 us; speedup vs baseline: 1.4423x; 1.0975x over previous
//
#include <hip/hip_runtime.h>
#include <hip/hip_bf16.h>

typedef __bf16 bf16;
typedef __bf16 bf16x8 __attribute__((ext_vector_type(8)));
typedef float f32x4 __attribute__((ext_vector_type(4)));

#define NB_ 6
#define E_ 512
#define NH_ 8
#define HS_ 64
#define FF_ 2048
#define B_ 16
#define T_ 512
#define M_ 8192   // B*T

// chunk swizzle: storage chunk = logical chunk ^ SW(row)  (chunks = 16B units)
#define SW(r) (((r) ^ ((r) >> 3)) & 7)

typedef const __attribute__((address_space(1))) void* gptr_t;
typedef __attribute__((address_space(3))) void* sptr_t;

// ---------------------------------------------------------------- weight prep
// wq/wk/wv [i][h][e][d] -> dst[i][c][e], c = which*512 + h*64 + d (bf16)
__global__ __launch_bounds__(256) void conv_qkv_tiled(
    const float* __restrict__ wq, const float* __restrict__ wk,
    const float* __restrict__ wv, bf16* __restrict__ dst)
{
    __shared__ float tile[32][65];          // [e][d], pad to 65
    const int e0 = blockIdx.x * 32;
    const int wh = blockIdx.y;              // 0..23
    const int which = wh >> 3, h = wh & 7;
    const int i = blockIdx.z;
    const float* src = (which == 0) ? wq : (which == 1) ? wk : wv;
    src += (((size_t)i * NH_ + h) * E_ + e0) * HS_;
    const int d = threadIdx.x & 63, er = threadIdx.x >> 6;    // 4 e-rows/pass
#pragma unroll
    for (int j = 0; j < 32; j += 4)
        tile[j + er][d] = src[(size_t)(j + er) * HS_ + d];
    __syncthreads();
    const int e = threadIdx.x & 31, dr = threadIdx.x >> 5;    // 8 d-rows/pass
    bf16* dbase = dst + (size_t)i * 1536 * E_ + ((size_t)which * 512 + h * 64) * E_ + e0;
#pragma unroll
    for (int j = 0; j < 64; j += 8)
        dbase[(size_t)(j + dr) * E_ + e] = (bf16)tile[e][j + dr];
}

// src[i][K][N] f32 -> dst[i][N][K] bf16 (tiled, coalesced both sides)
__global__ __launch_bounds__(256) void transpose_tiled(
    const float* __restrict__ src, bf16* __restrict__ dst, int K, int N)
{
    __shared__ float tile[32][33];
    const int n0 = blockIdx.x * 32, k0 = blockIdx.y * 32;
    const size_t sb = (size_t)blockIdx.z * K * N;
    const int lx = threadIdx.x & 31, ly = threadIdx.x >> 5;   // 8 rows/pass
#pragma unroll
    for (int j = 0; j < 32; j += 8)
        tile[j + ly][lx] = src[sb + (size_t)(k0 + j + ly) * N + n0 + lx];
    __syncthreads();
#pragma unroll
    for (int j = 0; j < 32; j += 8)
        dst[sb + (size_t)(n0 + j + ly) * K + k0 + lx] = (bf16)tile[lx][j + ly];
}

// ---------------------------------------------------------------- embed
__global__ __launch_bounds__(256) void embed_kernel(
    const int* __restrict__ x, const float* __restrict__ emb,
    const float* __restrict__ pos, float* __restrict__ h)
{
    int idx = blockIdx.x * 256 + threadIdx.x;   // per float4, M*128 total
    int row = idx >> 7;
    int e4 = (idx & 127) << 2;
    int tok = x[row];
    int t = row & (T_ - 1);
    float4 a = *(const float4*)&emb[(size_t)tok * E_ + e4];
    float4 c = *(const float4*)&pos[(size_t)t * E_ + e4];
    float4 o; o.x = a.x + c.x; o.y = a.y + c.y; o.z = a.z + c.z; o.w = a.w + c.w;
    *(float4*)&h[(size_t)row * E_ + e4] = o;
}

// ---------------------------------------------------------------- layernorm
template<int OUT_F32>
__global__ __launch_bounds__(256) void ln_kernel(
    const float* __restrict__ x, const float* __restrict__ gw,
    const float* __restrict__ bw, void* __restrict__ out)
{
    int wave = threadIdx.x >> 6, lane = threadIdx.x & 63;
    int row = blockIdx.x * 4 + wave;
    const float* xr = x + (size_t)row * E_;
    float4 v0 = *(const float4*)&xr[lane * 8];
    float4 v1 = *(const float4*)&xr[lane * 8 + 4];
    float vals[8] = {v0.x, v0.y, v0.z, v0.w, v1.x, v1.y, v1.z, v1.w};
    float s = 0.f, ss = 0.f;
#pragma unroll
    for (int j = 0; j < 8; ++j) { s += vals[j]; ss += vals[j] * vals[j]; }
#pragma unroll
    for (int m = 1; m < 64; m <<= 1) { s += __shfl_xor(s, m, 64); ss += __shfl_xor(ss, m, 64); }
    float mu = s * (1.f / E_);
    float var = ss * (1.f / E_) - mu * mu;
    float rs = rsqrtf(var + 1e-5f);
    int e0 = lane * 8;
    if (OUT_F32) {
        float* o = (float*)out + (size_t)row * E_ + e0;
#pragma unroll
        for (int j = 0; j < 8; ++j) o[j] = (vals[j] - mu) * rs * gw[e0 + j] + bw[e0 + j];
    } else {
        bf16x8 o;
#pragma unroll
        for (int j = 0; j < 8; ++j) o[j] = (bf16)((vals[j] - mu) * rs * gw[e0 + j] + bw[e0 + j]);
        *(bf16x8*)&((bf16*)out)[(size_t)row * E_ + e0] = o;
    }
}

// ---------------------------------------------------------------- GEMM (A[M][K] x Bt[N][K]^T)
// grid = (M/BM, N/BN): blockId = mi + (M/BM)*ni, so blockId%8 = mi%8 — all
// n-blocks sharing an A-panel land on the SAME XCD (kills A re-fetch, r8 PMC).
// BM=128, BN templated; BK=64; pre-swizzled source -> linear global_load_lds.
template<int BN_T, int HAS_BIAS, int HAS_RES, int RELU, int OUT_BF16>
__global__ __launch_bounds__(256) void gemm_bt(
    const bf16* __restrict__ A, const bf16* __restrict__ Bt,
    const float* __restrict__ bias, const float* __restrict__ res,
    void* __restrict__ out, int M, int N, int K)
{
    constexpr int BM = 128, BK = 64;
    constexpr int NI = BN_T / 32;          // n-frags per wave (wave n-tile = BN_T/2)
    __shared__ bf16 As[BM * BK];
    __shared__ bf16 Bs[BN_T * BK];
    const int tid = threadIdx.x;
    const int wave = tid >> 6, lane = tid & 63;
    const int l15 = lane & 15, g = lane >> 4;
    const int m0 = blockIdx.x * BM, n0 = blockIdx.y * BN_T;
    const int wm = (wave >> 1) * 64, wn = (wave & 1) * (BN_T / 2);
    const int sr = tid >> 3, sc = tid & 7;   // staging: row base, chunk
    f32x4 acc[4][NI] = {};
    for (int k0 = 0; k0 < K; k0 += BK) {
        __syncthreads();
#pragma unroll
        for (int p = 0; p < 4; ++p) {
            int row = p * 32 + sr;
            int cg = sc ^ SW(row);           // pre-swizzled source chunk
            __builtin_amdgcn_global_load_lds(
                (gptr_t)&A[(size_t)(m0 + row) * K + k0 + cg * 8],
                (sptr_t)&As[row * 64 + sc * 8], 16, 0, 0);
        }
#pragma unroll
        for (int p = 0; p < BN_T / 32; ++p) {
            int row = p * 32 + sr;
            int cg = sc ^ SW(row);
            __builtin_amdgcn_global_load_lds(
                (gptr_t)&Bt[(size_t)(n0 + row) * K + k0 + cg * 8],
                (sptr_t)&Bs[row * 64 + sc * 8], 16, 0, 0);
        }
        __syncthreads();
#pragma unroll
        for (int kk = 0; kk < 2; ++kk) {
            bf16x8 af[4], bg[NI];
#pragma unroll
            for (int mi = 0; mi < 4; ++mi) {
                int row = wm + 16 * mi + l15;
                af[mi] = *(const bf16x8*)&As[row * 64 + ((kk * 4 + g) ^ SW(row)) * 8];
            }
#pragma unroll
            for (int ni = 0; ni < NI; ++ni) {
                int row = wn + 16 * ni + l15;
                bg[ni] = *(const bf16x8*)&Bs[row * 64 + ((kk * 4 + g) ^ SW(row)) * 8];
            }
#pragma unroll
            for (int mi = 0; mi < 4; ++mi)
#pragma unroll
                for (int ni = 0; ni < NI; ++ni)
                    acc[mi][ni] = __builtin_amdgcn_mfma_f32_16x16x32_bf16(
                        af[mi], bg[ni], acc[mi][ni], 0, 0, 0);
        }
    }
    // epilogue: C/D layout col=lane&15, row=(lane>>4)*4+reg  [measured m89]
#pragma unroll
    for (int mi = 0; mi < 4; ++mi) {
#pragma unroll
        for (int ni = 0; ni < NI; ++ni) {
#pragma unroll
            for (int r = 0; r < 4; ++r) {
                int rr = m0 + wm + 16 * mi + 4 * g + r;
                int cc = n0 + wn + 16 * ni + l15;
                float v = acc[mi][ni][r];
                if (HAS_BIAS) v += bias[cc];
                if (HAS_RES) v += res[(size_t)rr * N + cc];
                if (RELU) v = fmaxf(v, 0.f);
                if (OUT_BF16) ((bf16*)out)[(size_t)rr * N + cc] = (bf16)v;
                else ((float*)out)[(size_t)rr * N + cc] = v;
            }
        }
    }
}

// ---------------------------------------------------------------- attention
// qkv: [B*T][1536] bf16 (q|k|v, col = h*64+d). out: [B*T][512] bf16.
// grid: (B*NH, 4 pairs): blockId%8 = bh%8, so both pair-blocks of one (b,h)
// (sharing K/V) land on the same XCD. pair p handles q-tiles p and 7-p.
__global__ __launch_bounds__(256) void attn_kernel(
    const bf16* __restrict__ qkv, bf16* __restrict__ out)
{
    constexpr int RS = 3 * E_;   // 1536 row stride
    __shared__ bf16 Ks[64 * 64];
    __shared__ bf16 Vt[64 * 64];
    __shared__ bf16 Ps[4][16 * 64];
    const int tid = threadIdx.x;
    const int wave = tid >> 6, lane = tid & 63;
    const int l15 = lane & 15, g = lane >> 4;
    const int bh = blockIdx.x;
    const int b = bh >> 3, h = bh & 7;
    const size_t base = (size_t)b * T_ * RS;
    const bf16* kb = qkv + base + E_ + h * HS_;
    const bf16* vb = qkv + base + 2 * E_ + h * HS_;
    const int strow = tid >> 3, stc = tid & 7;   // staging row/chunk

    for (int half = 0; half < 2; ++half) {
        const int qt = half == 0 ? (int)blockIdx.y : 7 - (int)blockIdx.y;
        const int q0 = qt * 64;
        const int ntiles = qt + 1;
        bf16x8 qf[2];
        {
            const bf16* qrow = qkv + base + (size_t)(q0 + wave * 16 + l15) * RS + h * HS_;
            qf[0] = *(const bf16x8*)&qrow[8 * g];
            qf[1] = *(const bf16x8*)&qrow[32 + 8 * g];
        }
        float mrow[4] = {-1e30f, -1e30f, -1e30f, -1e30f};
        float lrow[4] = {0.f, 0.f, 0.f, 0.f};
        f32x4 accO[4] = {};
        // prefetch tile 0 into regs
        bf16x8 kreg[2], vreg[2];
#pragma unroll
        for (int r = 0; r < 2; ++r) {
            int krow = r * 32 + strow;
            kreg[r] = *(const bf16x8*)&kb[(size_t)krow * RS + stc * 8];
            vreg[r] = *(const bf16x8*)&vb[(size_t)krow * RS + stc * 8];
        }
        for (int tile = 0; tile < ntiles; ++tile) {
            __syncthreads();   // previous compute done, LDS free
            // write staged regs -> LDS (swizzled)
#pragma unroll
            for (int r = 0; r < 2; ++r) {
                int krow = r * 32 + strow;
                *(bf16x8*)&Ks[krow * 64 + (stc ^ SW(krow)) * 8] = kreg[r];
#pragma unroll
                for (int j = 0; j < 8; ++j) {
                    int drow = stc * 8 + j;
                    Vt[drow * 64 + ((krow >> 3) ^ SW(drow)) * 8 + (krow & 7)] = vreg[r][j];
                }
            }
            // prefetch next tile (overlaps with compute below)
            if (tile + 1 < ntiles) {
                int kv = (tile + 1) * 64;
#pragma unroll
                for (int r = 0; r < 2; ++r) {
                    int krow = kv + r * 32 + strow;
                    kreg[r] = *(const bf16x8*)&kb[(size_t)krow * RS + stc * 8];
                    vreg[r] = *(const bf16x8*)&vb[(size_t)krow * RS + stc * 8];
                }
            }
            __syncthreads();
            // S = Q K^T  (S[q=4g+r][kv=16t+l15] per lane)
            f32x4 accS[4] = {};
#pragma unroll
            for (int t = 0; t < 4; ++t) {
                int rk = 16 * t + l15;
#pragma unroll
                for (int kc = 0; kc < 2; ++kc) {
                    bf16x8 kf = *(const bf16x8*)&Ks[rk * 64 + ((kc * 4 + g) ^ SW(rk)) * 8];
                    accS[t] = __builtin_amdgcn_mfma_f32_16x16x32_bf16(qf[kc], kf, accS[t], 0, 0, 0);
                }
            }
            float sarr[4][4];
            const bool diag = (tile == qt);
#pragma unroll
            for (int t = 0; t < 4; ++t)
#pragma unroll
                for (int r = 0; r < 4; ++r) {
                    float s = accS[t][r] * 0.125f;   // HS^-0.5
                    if (diag && (16 * t + l15 > 16 * wave + 4 * g + r)) s = -1e30f;
                    sarr[t][r] = s;
                }
            float alpha[4];
#pragma unroll
            for (int r = 0; r < 4; ++r) {
                float mx = fmaxf(fmaxf(sarr[0][r], sarr[1][r]), fmaxf(sarr[2][r], sarr[3][r]));
#pragma unroll
                for (int m = 1; m < 16; m <<= 1) mx = fmaxf(mx, __shfl_xor(mx, m, 64));
                float mnew = fmaxf(mrow[r], mx);
                alpha[r] = __expf(mrow[r] - mnew);
                mrow[r] = mnew;
            }
#pragma unroll
            for (int t = 0; t < 4; ++t)
#pragma unroll
                for (int r = 0; r < 4; ++r) sarr[t][r] = __expf(sarr[t][r] - mrow[r]);
#pragma unroll
            for (int r = 0; r < 4; ++r) {
                float rs0 = sarr[0][r] + sarr[1][r] + sarr[2][r] + sarr[3][r];
#pragma unroll
                for (int m = 1; m < 16; m <<= 1) rs0 += __shfl_xor(rs0, m, 64);
                lrow[r] = lrow[r] * alpha[r] + rs0;
            }
#pragma unroll
            for (int u = 0; u < 4; ++u)
#pragma unroll
                for (int r = 0; r < 4; ++r) accO[u][r] *= alpha[r];
            // P -> LDS (wave-private, swizzled), then PV
#pragma unroll
            for (int t = 0; t < 4; ++t)
#pragma unroll
                for (int r = 0; r < 4; ++r) {
                    int prow = 4 * g + r;
                    Ps[wave][prow * 64 + ((2 * t + (l15 >> 3)) ^ SW(prow)) * 8 + (l15 & 7)] =
                        (bf16)sarr[t][r];
                }
#pragma unroll
            for (int kc = 0; kc < 2; ++kc) {
                bf16x8 pf = *(const bf16x8*)&Ps[wave][l15 * 64 + ((kc * 4 + g) ^ SW(l15)) * 8];
#pragma unroll
                for (int u = 0; u < 4; ++u) {
                    int rv = 16 * u + l15;
                    bf16x8 vf = *(const bf16x8*)&Vt[rv * 64 + ((kc * 4 + g) ^ SW(rv)) * 8];
                    accO[u] = __builtin_amdgcn_mfma_f32_16x16x32_bf16(pf, vf, accO[u], 0, 0, 0);
                }
            }
        }
#pragma unroll
        for (int u = 0; u < 4; ++u)
#pragma unroll
            for (int r = 0; r < 4; ++r) {
                int row = q0 + 16 * wave + 4 * g + r;
                out[((size_t)b * T_ + row) * E_ + h * HS_ + 16 * u + l15] =
                    (bf16)(accO[u][r] / lrow[r]);
            }
    }
}

// ---------------------------------------------------------------- out projection (fp32)
__global__ __launch_bounds__(256) void outproj_kernel(
    const float* __restrict__ hn, const float* __restrict__ W,
    const float* __restrict__ bias, float* __restrict__ out)
{
    int idx = blockIdx.x * 256 + threadIdx.x;   // M*16
    int row = idx >> 4, v = idx & 15;
    const float* hr = hn + (size_t)row * E_;
    float acc = 0.f;
#pragma unroll 8
    for (int k = 0; k < E_; ++k) acc += hr[k] * W[k * 16 + v];
    out[idx] = (acc + bias[v]) * 1.25f;   // 1/TEMP, TEMP=0.8
}

// ---------------------------------------------------------------- host
extern "C" void kernel_launch(void* const* d_in, const int* in_sizes, int n_in,
                              void* d_out, int out_size, void* d_ws, size_t ws_size,
                              hipStream_t stream)
{
    const int*   x      = (const int*)d_in[0];
    const float* emb    = (const float*)d_in[1];
    const float* pos    = (const float*)d_in[2];
    const float* wq     = (const float*)d_in[3];
    const float* wk     = (const float*)d_in[4];
    const float* wv     = (const float*)d_in[5];
    const float* proj_w = (const float*)d_in[6];
    const float* proj_b = (const float*)d_in[7];
    const float* ln1_g  = (const float*)d_in[8];
    const float* ln1_b  = (const float*)d_in[9];
    const float* ln2_g  = (const float*)d_in[10];
    const float* ln2_b  = (const float*)d_in[11];
    const float* ff_w1  = (const float*)d_in[12];
    const float* ff_b1  = (const float*)d_in[13];
    const float* ff_w2  = (const float*)d_in[14];
    const float* ff_b2  = (const float*)d_in[15];
    const float* lnf_g  = (const float*)d_in[16];
    const float* lnf_b  = (const float*)d_in[17];
    const float* out_w  = (const float*)d_in[18];
    const float* out_b  = (const float*)d_in[19];

    char* ws = (char*)d_ws;
    size_t off = 0;
    auto alloc = [&](size_t bytes) { size_t r = off; off += (bytes + 255) & ~(size_t)255; return r; };
    bf16*  wqkv_t = (bf16*)(ws + alloc((size_t)NB_ * 1536 * 512 * 2));
    bf16*  projt  = (bf16*)(ws + alloc((size_t)NB_ * 512 * 512 * 2));
    bf16*  ff1t   = (bf16*)(ws + alloc((size_t)NB_ * 2048 * 512 * 2));
    bf16*  ff2t   = (bf16*)(ws + alloc((size_t)NB_ * 512 * 2048 * 2));
    float* h      = (float*)(ws + alloc((size_t)M_ * 512 * 4));
    bf16*  xn     = (bf16*)(ws + alloc((size_t)M_ * 512 * 2));
    bf16*  qkvb   = (bf16*)(ws + alloc((size_t)M_ * 1536 * 2));
    bf16*  aout   = (bf16*)(ws + alloc((size_t)M_ * 512 * 2));
    bf16*  ffact  = (bf16*)(ws + alloc((size_t)M_ * 2048 * 2));
    float* hn     = (float*)(ws + alloc((size_t)M_ * 512 * 4));
    (void)ws_size; (void)in_sizes; (void)n_in; (void)out_size;

    // weight prep (tiled, coalesced)
    conv_qkv_tiled<<<dim3(16, 24, NB_), 256, 0, stream>>>(wq, wk, wv, wqkv_t);
    transpose_tiled<<<dim3(512 / 32, 512 / 32, NB_), 256, 0, stream>>>(proj_w, projt, 512, 512);
    transpose_tiled<<<dim3(2048 / 32, 512 / 32, NB_), 256, 0, stream>>>(ff_w1, ff1t, 512, 2048);
    transpose_tiled<<<dim3(512 / 32, 2048 / 32, NB_), 256, 0, stream>>>(ff_w2, ff2t, 2048, 512);

    embed_kernel<<<(M_ * 128) / 256, 256, 0, stream>>>(x, emb, pos, h);

    for (int i = 0; i < NB_; ++i) {
        ln_kernel<0><<<M_ / 4, 256, 0, stream>>>(h, ln1_g + i * 512, ln1_b + i * 512, xn);
        gemm_bt<128, 0, 0, 0, 1><<<dim3(M_ / 128, 1536 / 128), 256, 0, stream>>>(
            xn, wqkv_t + (size_t)i * 1536 * 512, nullptr, nullptr, qkvb, M_, 1536, 512);
        attn_kernel<<<dim3(B_ * NH_, 4), 256, 0, stream>>>(qkvb, aout);
        gemm_bt<64, 1, 1, 0, 0><<<dim3(M_ / 128, 512 / 64), 256, 0, stream>>>(
            aout, projt + (size_t)i * 512 * 512, proj_b + i * 512, h, h, M_, 512, 512);
        ln_kernel<0><<<M_ / 4, 256, 0, stream>>>(h, ln2_g + i * 512, ln2_b + i * 512, xn);
        gemm_bt<128, 1, 0, 1, 1><<<dim3(M_ / 128, 2048 / 128), 256, 0, stream>>>(
            xn, ff1t + (size_t)i * 2048 * 512, ff_b1 + i * 2048, nullptr, ffact, M_, 2048, 512);
        gemm_bt<64, 1, 1, 0, 0><<<dim3(M_ / 128, 512 / 64), 256, 0, stream>>>(
            ffact, ff2t + (size_t)i * 512 * 2048, ff_b2 + i * 512, h, h, M_, 512, 2048);
    }
    ln_kernel<1><<<M_ / 4, 256, 0, stream>>>(h, lnf_g, lnf_b, hn);
    outproj_kernel<<<(M_ * 16) / 256, 256, 0, stream>>>(hn, out_w, out_b, (float*)d_out);
}

// Round 10
// 915.145 us; speedup vs baseline: 1.4770x; 1.0240x over previous
//
#include <hip/hip_runtime.h>
#include <hip/hip_bf16.h>

typedef __bf16 bf16;
typedef __bf16 bf16x8 __attribute__((ext_vector_type(8)));
typedef float f32x4 __attribute__((ext_vector_type(4)));

#define NB_ 6
#define E_ 512
#define NH_ 8
#define HS_ 64
#define FF_ 2048
#define B_ 16
#define T_ 512
#define M_ 8192   // B*T

// chunk swizzle: storage chunk = logical chunk ^ SW(row)  (chunks = 16B units)
#define SW(r) (((r) ^ ((r) >> 3)) & 7)

typedef const __attribute__((address_space(1))) void* gptr_t;
typedef __attribute__((address_space(3))) void* sptr_t;

// ---------------------------------------------------------------- weight prep
// wq/wk/wv [i][h][e][d] -> dst[i][c][e], c = which*512 + h*64 + d (bf16)
__global__ __launch_bounds__(256) void conv_qkv_tiled(
    const float* __restrict__ wq, const float* __restrict__ wk,
    const float* __restrict__ wv, bf16* __restrict__ dst)
{
    __shared__ float tile[32][65];          // [e][d], pad to 65
    const int e0 = blockIdx.x * 32;
    const int wh = blockIdx.y;              // 0..23
    const int which = wh >> 3, h = wh & 7;
    const int i = blockIdx.z;
    const float* src = (which == 0) ? wq : (which == 1) ? wk : wv;
    src += (((size_t)i * NH_ + h) * E_ + e0) * HS_;
    const int d = threadIdx.x & 63, er = threadIdx.x >> 6;    // 4 e-rows/pass
#pragma unroll
    for (int j = 0; j < 32; j += 4)
        tile[j + er][d] = src[(size_t)(j + er) * HS_ + d];
    __syncthreads();
    const int e = threadIdx.x & 31, dr = threadIdx.x >> 5;    // 8 d-rows/pass
    bf16* dbase = dst + (size_t)i * 1536 * E_ + ((size_t)which * 512 + h * 64) * E_ + e0;
#pragma unroll
    for (int j = 0; j < 64; j += 8)
        dbase[(size_t)(j + dr) * E_ + e] = (bf16)tile[e][j + dr];
}

// src[i][K][N] f32 -> dst[i][N][K] bf16 (tiled, coalesced both sides)
__global__ __launch_bounds__(256) void transpose_tiled(
    const float* __restrict__ src, bf16* __restrict__ dst, int K, int N)
{
    __shared__ float tile[32][33];
    const int n0 = blockIdx.x * 32, k0 = blockIdx.y * 32;
    const size_t sb = (size_t)blockIdx.z * K * N;
    const int lx = threadIdx.x & 31, ly = threadIdx.x >> 5;   // 8 rows/pass
#pragma unroll
    for (int j = 0; j < 32; j += 8)
        tile[j + ly][lx] = src[sb + (size_t)(k0 + j + ly) * N + n0 + lx];
    __syncthreads();
#pragma unroll
    for (int j = 0; j < 32; j += 8)
        dst[sb + (size_t)(n0 + j + ly) * K + k0 + lx] = (bf16)tile[lx][j + ly];
}

// ---------------------------------------------------------------- embed
__global__ __launch_bounds__(256) void embed_kernel(
    const int* __restrict__ x, const float* __restrict__ emb,
    const float* __restrict__ pos, float* __restrict__ h)
{
    int idx = blockIdx.x * 256 + threadIdx.x;   // per float4, M*128 total
    int row = idx >> 7;
    int e4 = (idx & 127) << 2;
    int tok = x[row];
    int t = row & (T_ - 1);
    float4 a = *(const float4*)&emb[(size_t)tok * E_ + e4];
    float4 c = *(const float4*)&pos[(size_t)t * E_ + e4];
    float4 o; o.x = a.x + c.x; o.y = a.y + c.y; o.z = a.z + c.z; o.w = a.w + c.w;
    *(float4*)&h[(size_t)row * E_ + e4] = o;
}

// ---------------------------------------------------------------- layernorm
template<int OUT_F32>
__global__ __launch_bounds__(256) void ln_kernel(
    const float* __restrict__ x, const float* __restrict__ gw,
    const float* __restrict__ bw, void* __restrict__ out)
{
    int wave = threadIdx.x >> 6, lane = threadIdx.x & 63;
    int row = blockIdx.x * 4 + wave;
    const float* xr = x + (size_t)row * E_;
    float4 v0 = *(const float4*)&xr[lane * 8];
    float4 v1 = *(const float4*)&xr[lane * 8 + 4];
    float vals[8] = {v0.x, v0.y, v0.z, v0.w, v1.x, v1.y, v1.z, v1.w};
    float s = 0.f, ss = 0.f;
#pragma unroll
    for (int j = 0; j < 8; ++j) { s += vals[j]; ss += vals[j] * vals[j]; }
#pragma unroll
    for (int m = 1; m < 64; m <<= 1) { s += __shfl_xor(s, m, 64); ss += __shfl_xor(ss, m, 64); }
    float mu = s * (1.f / E_);
    float var = ss * (1.f / E_) - mu * mu;
    float rs = rsqrtf(var + 1e-5f);
    int e0 = lane * 8;
    if (OUT_F32) {
        float* o = (float*)out + (size_t)row * E_ + e0;
#pragma unroll
        for (int j = 0; j < 8; ++j) o[j] = (vals[j] - mu) * rs * gw[e0 + j] + bw[e0 + j];
    } else {
        bf16x8 o;
#pragma unroll
        for (int j = 0; j < 8; ++j) o[j] = (bf16)((vals[j] - mu) * rs * gw[e0 + j] + bw[e0 + j]);
        *(bf16x8*)&((bf16*)out)[(size_t)row * E_ + e0] = o;
    }
}

// ---------------------------------------------------------------- GEMM (A[M][K] x Bt[N][K]^T)
// grid = (M/BM, N/BN): blockId%8 = mi%8 — n-blocks sharing an A-panel land on
// the same XCD (verified r9: fetch amplification gone, -91 us).
// BN=64 path: 2-phase double-buffered pipeline (T3/T4) — stage next K-tile
// before compute, counted vmcnt(6) + raw s_barrier (never drain to 0 mid-loop).
// BN=128 path: unchanged serial (dbuf would halve its 4 blocks/CU — m132).
template<int BN_T, int HAS_BIAS, int HAS_RES, int RELU, int OUT_BF16>
__global__ __launch_bounds__(256) void gemm_bt(
    const bf16* __restrict__ A, const bf16* __restrict__ Bt,
    const float* __restrict__ bias, const float* __restrict__ res,
    void* __restrict__ out, int M, int N, int K)
{
    constexpr int BM = 128, BK = 64;
    constexpr int NI = BN_T / 32;          // n-frags per wave (wave n-tile = BN_T/2)
    constexpr bool DBUF = (BN_T == 64);
    constexpr int NBUF = DBUF ? 2 : 1;
    __shared__ bf16 As[NBUF][BM * BK];
    __shared__ bf16 Bs[NBUF][BN_T * BK];
    const int tid = threadIdx.x;
    const int wave = tid >> 6, lane = tid & 63;
    const int l15 = lane & 15, g = lane >> 4;
    const int m0 = blockIdx.x * BM, n0 = blockIdx.y * BN_T;
    const int wm = (wave >> 1) * 64, wn = (wave & 1) * (BN_T / 2);
    const int sr = tid >> 3, sc = tid & 7;   // staging: row base, chunk
    f32x4 acc[4][NI] = {};

    auto stage = [&](int buf, int k0) {
#pragma unroll
        for (int p = 0; p < 4; ++p) {
            int row = p * 32 + sr;
            int cg = sc ^ SW(row);           // pre-swizzled source chunk
            __builtin_amdgcn_global_load_lds(
                (gptr_t)&A[(size_t)(m0 + row) * K + k0 + cg * 8],
                (sptr_t)&As[buf][row * 64 + sc * 8], 16, 0, 0);
        }
#pragma unroll
        for (int p = 0; p < BN_T / 32; ++p) {
            int row = p * 32 + sr;
            int cg = sc ^ SW(row);
            __builtin_amdgcn_global_load_lds(
                (gptr_t)&Bt[(size_t)(n0 + row) * K + k0 + cg * 8],
                (sptr_t)&Bs[buf][row * 64 + sc * 8], 16, 0, 0);
        }
    };
    auto compute = [&](int buf) {
#pragma unroll
        for (int kk = 0; kk < 2; ++kk) {
            bf16x8 af[4], bg[NI];
#pragma unroll
            for (int mi = 0; mi < 4; ++mi) {
                int row = wm + 16 * mi + l15;
                af[mi] = *(const bf16x8*)&As[buf][row * 64 + ((kk * 4 + g) ^ SW(row)) * 8];
            }
#pragma unroll
            for (int ni = 0; ni < NI; ++ni) {
                int row = wn + 16 * ni + l15;
                bg[ni] = *(const bf16x8*)&Bs[buf][row * 64 + ((kk * 4 + g) ^ SW(row)) * 8];
            }
#pragma unroll
            for (int mi = 0; mi < 4; ++mi)
#pragma unroll
                for (int ni = 0; ni < NI; ++ni)
                    acc[mi][ni] = __builtin_amdgcn_mfma_f32_16x16x32_bf16(
                        af[mi], bg[ni], acc[mi][ni], 0, 0, 0);
        }
    };

    if constexpr (DBUF) {
        const int nt = K / BK;
        stage(0, 0);                       // NLOAD=6 VMEM ops/wave in flight
        int cur = 0;
        for (int t = 0; t < nt; ++t) {
            if (t + 1 < nt) {
                stage(cur ^ 1, (t + 1) * BK);
                asm volatile("s_waitcnt vmcnt(6)" ::: "memory");  // wait OLDER group only
            } else {
                asm volatile("s_waitcnt vmcnt(0)" ::: "memory");
            }
            __builtin_amdgcn_s_barrier();  // all waves' tile-t loads landed
            compute(cur);
            __builtin_amdgcn_s_barrier();  // LDS free before next overwrite
            asm volatile("" ::: "memory");
            cur ^= 1;
        }
    } else {
        for (int k0 = 0; k0 < K; k0 += BK) {
            __syncthreads();
            stage(0, k0);
            __syncthreads();
            compute(0);
        }
    }

    // epilogue: C/D layout col=lane&15, row=(lane>>4)*4+reg  [measured m89]
#pragma unroll
    for (int mi = 0; mi < 4; ++mi) {
#pragma unroll
        for (int ni = 0; ni < NI; ++ni) {
#pragma unroll
            for (int r = 0; r < 4; ++r) {
                int rr = m0 + wm + 16 * mi + 4 * g + r;
                int cc = n0 + wn + 16 * ni + l15;
                float v = acc[mi][ni][r];
                if (HAS_BIAS) v += bias[cc];
                if (HAS_RES) v += res[(size_t)rr * N + cc];
                if (RELU) v = fmaxf(v, 0.f);
                if (OUT_BF16) ((bf16*)out)[(size_t)rr * N + cc] = (bf16)v;
                else ((float*)out)[(size_t)rr * N + cc] = v;
            }
        }
    }
}

// ---------------------------------------------------------------- attention
// qkv: [B*T][1536] bf16 (q|k|v, col = h*64+d). out: [B*T][512] bf16.
// grid: (B*NH, 4 pairs): blockId%8 = bh%8 — pair-blocks sharing K/V on one XCD.
__global__ __launch_bounds__(256) void attn_kernel(
    const bf16* __restrict__ qkv, bf16* __restrict__ out)
{
    constexpr int RS = 3 * E_;   // 1536 row stride
    __shared__ bf16 Ks[64 * 64];
    __shared__ bf16 Vt[64 * 64];
    __shared__ bf16 Ps[4][16 * 64];
    const int tid = threadIdx.x;
    const int wave = tid >> 6, lane = tid & 63;
    const int l15 = lane & 15, g = lane >> 4;
    const int bh = blockIdx.x;
    const int b = bh >> 3, h = bh & 7;
    const size_t base = (size_t)b * T_ * RS;
    const bf16* kb = qkv + base + E_ + h * HS_;
    const bf16* vb = qkv + base + 2 * E_ + h * HS_;
    const int strow = tid >> 3, stc = tid & 7;   // staging row/chunk

    for (int half = 0; half < 2; ++half) {
        const int qt = half == 0 ? (int)blockIdx.y : 7 - (int)blockIdx.y;
        const int q0 = qt * 64;
        const int ntiles = qt + 1;
        bf16x8 qf[2];
        {
            const bf16* qrow = qkv + base + (size_t)(q0 + wave * 16 + l15) * RS + h * HS_;
            qf[0] = *(const bf16x8*)&qrow[8 * g];
            qf[1] = *(const bf16x8*)&qrow[32 + 8 * g];
        }
        float mrow[4] = {-1e30f, -1e30f, -1e30f, -1e30f};
        float lrow[4] = {0.f, 0.f, 0.f, 0.f};
        f32x4 accO[4] = {};
        // prefetch tile 0 into regs
        bf16x8 kreg[2], vreg[2];
#pragma unroll
        for (int r = 0; r < 2; ++r) {
            int krow = r * 32 + strow;
            kreg[r] = *(const bf16x8*)&kb[(size_t)krow * RS + stc * 8];
            vreg[r] = *(const bf16x8*)&vb[(size_t)krow * RS + stc * 8];
        }
        for (int tile = 0; tile < ntiles; ++tile) {
            __syncthreads();   // previous compute done, LDS free
            // write staged regs -> LDS (swizzled)
#pragma unroll
            for (int r = 0; r < 2; ++r) {
                int krow = r * 32 + strow;
                *(bf16x8*)&Ks[krow * 64 + (stc ^ SW(krow)) * 8] = kreg[r];
#pragma unroll
                for (int j = 0; j < 8; ++j) {
                    int drow = stc * 8 + j;
                    Vt[drow * 64 + ((krow >> 3) ^ SW(drow)) * 8 + (krow & 7)] = vreg[r][j];
                }
            }
            // prefetch next tile (overlaps with compute below)
            if (tile + 1 < ntiles) {
                int kv = (tile + 1) * 64;
#pragma unroll
                for (int r = 0; r < 2; ++r) {
                    int krow = kv + r * 32 + strow;
                    kreg[r] = *(const bf16x8*)&kb[(size_t)krow * RS + stc * 8];
                    vreg[r] = *(const bf16x8*)&vb[(size_t)krow * RS + stc * 8];
                }
            }
            __syncthreads();
            // S = Q K^T  (S[q=4g+r][kv=16t+l15] per lane)
            f32x4 accS[4] = {};
#pragma unroll
            for (int t = 0; t < 4; ++t) {
                int rk = 16 * t + l15;
#pragma unroll
                for (int kc = 0; kc < 2; ++kc) {
                    bf16x8 kf = *(const bf16x8*)&Ks[rk * 64 + ((kc * 4 + g) ^ SW(rk)) * 8];
                    accS[t] = __builtin_amdgcn_mfma_f32_16x16x32_bf16(qf[kc], kf, accS[t], 0, 0, 0);
                }
            }
            float sarr[4][4];
            const bool diag = (tile == qt);
#pragma unroll
            for (int t = 0; t < 4; ++t)
#pragma unroll
                for (int r = 0; r < 4; ++r) {
                    float s = accS[t][r] * 0.125f;   // HS^-0.5
                    if (diag && (16 * t + l15 > 16 * wave + 4 * g + r)) s = -1e30f;
                    sarr[t][r] = s;
                }
            float alpha[4];
#pragma unroll
            for (int r = 0; r < 4; ++r) {
                float mx = fmaxf(fmaxf(sarr[0][r], sarr[1][r]), fmaxf(sarr[2][r], sarr[3][r]));
#pragma unroll
                for (int m = 1; m < 16; m <<= 1) mx = fmaxf(mx, __shfl_xor(mx, m, 64));
                float mnew = fmaxf(mrow[r], mx);
                alpha[r] = __expf(mrow[r] - mnew);
                mrow[r] = mnew;
            }
#pragma unroll
            for (int t = 0; t < 4; ++t)
#pragma unroll
                for (int r = 0; r < 4; ++r) sarr[t][r] = __expf(sarr[t][r] - mrow[r]);
#pragma unroll
            for (int r = 0; r < 4; ++r) {
                float rs0 = sarr[0][r] + sarr[1][r] + sarr[2][r] + sarr[3][r];
#pragma unroll
                for (int m = 1; m < 16; m <<= 1) rs0 += __shfl_xor(rs0, m, 64);
                lrow[r] = lrow[r] * alpha[r] + rs0;
            }
#pragma unroll
            for (int u = 0; u < 4; ++u)
#pragma unroll
                for (int r = 0; r < 4; ++r) accO[u][r] *= alpha[r];
            // P -> LDS (wave-private, swizzled), then PV
#pragma unroll
            for (int t = 0; t < 4; ++t)
#pragma unroll
                for (int r = 0; r < 4; ++r) {
                    int prow = 4 * g + r;
                    Ps[wave][prow * 64 + ((2 * t + (l15 >> 3)) ^ SW(prow)) * 8 + (l15 & 7)] =
                        (bf16)sarr[t][r];
                }
#pragma unroll
            for (int kc = 0; kc < 2; ++kc) {
                bf16x8 pf = *(const bf16x8*)&Ps[wave][l15 * 64 + ((kc * 4 + g) ^ SW(l15)) * 8];
#pragma unroll
                for (int u = 0; u < 4; ++u) {
                    int rv = 16 * u + l15;
                    bf16x8 vf = *(const bf16x8*)&Vt[rv * 64 + ((kc * 4 + g) ^ SW(rv)) * 8];
                    accO[u] = __builtin_amdgcn_mfma_f32_16x16x32_bf16(pf, vf, accO[u], 0, 0, 0);
                }
            }
        }
#pragma unroll
        for (int u = 0; u < 4; ++u)
#pragma unroll
            for (int r = 0; r < 4; ++r) {
                int row = q0 + 16 * wave + 4 * g + r;
                out[((size_t)b * T_ + row) * E_ + h * HS_ + 16 * u + l15] =
                    (bf16)(accO[u][r] / lrow[r]);
            }
    }
}

// ---------------------------------------------------------------- out projection (fp32)
__global__ __launch_bounds__(256) void outproj_kernel(
    const float* __restrict__ hn, const float* __restrict__ W,
    const float* __restrict__ bias, float* __restrict__ out)
{
    int idx = blockIdx.x * 256 + threadIdx.x;   // M*16
    int row = idx >> 4, v = idx & 15;
    const float* hr = hn + (size_t)row * E_;
    float acc = 0.f;
#pragma unroll 8
    for (int k = 0; k < E_; ++k) acc += hr[k] * W[k * 16 + v];
    out[idx] = (acc + bias[v]) * 1.25f;   // 1/TEMP, TEMP=0.8
}

// ---------------------------------------------------------------- host
extern "C" void kernel_launch(void* const* d_in, const int* in_sizes, int n_in,
                              void* d_out, int out_size, void* d_ws, size_t ws_size,
                              hipStream_t stream)
{
    const int*   x      = (const int*)d_in[0];
    const float* emb    = (const float*)d_in[1];
    const float* pos    = (const float*)d_in[2];
    const float* wq     = (const float*)d_in[3];
    const float* wk     = (const float*)d_in[4];
    const float* wv     = (const float*)d_in[5];
    const float* proj_w = (const float*)d_in[6];
    const float* proj_b = (const float*)d_in[7];
    const float* ln1_g  = (const float*)d_in[8];
    const float* ln1_b  = (const float*)d_in[9];
    const float* ln2_g  = (const float*)d_in[10];
    const float* ln2_b  = (const float*)d_in[11];
    const float* ff_w1  = (const float*)d_in[12];
    const float* ff_b1  = (const float*)d_in[13];
    const float* ff_w2  = (const float*)d_in[14];
    const float* ff_b2  = (const float*)d_in[15];
    const float* lnf_g  = (const float*)d_in[16];
    const float* lnf_b  = (const float*)d_in[17];
    const float* out_w  = (const float*)d_in[18];
    const float* out_b  = (const float*)d_in[19];

    char* ws = (char*)d_ws;
    size_t off = 0;
    auto alloc = [&](size_t bytes) { size_t r = off; off += (bytes + 255) & ~(size_t)255; return r; };
    bf16*  wqkv_t = (bf16*)(ws + alloc((size_t)NB_ * 1536 * 512 * 2));
    bf16*  projt  = (bf16*)(ws + alloc((size_t)NB_ * 512 * 512 * 2));
    bf16*  ff1t   = (bf16*)(ws + alloc((size_t)NB_ * 2048 * 512 * 2));
    bf16*  ff2t   = (bf16*)(ws + alloc((size_t)NB_ * 512 * 2048 * 2));
    float* h      = (float*)(ws + alloc((size_t)M_ * 512 * 4));
    bf16*  xn     = (bf16*)(ws + alloc((size_t)M_ * 512 * 2));
    bf16*  qkvb   = (bf16*)(ws + alloc((size_t)M_ * 1536 * 2));
    bf16*  aout   = (bf16*)(ws + alloc((size_t)M_ * 512 * 2));
    bf16*  ffact  = (bf16*)(ws + alloc((size_t)M_ * 2048 * 2));
    float* hn     = (float*)(ws + alloc((size_t)M_ * 512 * 4));
    (void)ws_size; (void)in_sizes; (void)n_in; (void)out_size;

    // weight prep (tiled, coalesced)
    conv_qkv_tiled<<<dim3(16, 24, NB_), 256, 0, stream>>>(wq, wk, wv, wqkv_t);
    transpose_tiled<<<dim3(512 / 32, 512 / 32, NB_), 256, 0, stream>>>(proj_w, projt, 512, 512);
    transpose_tiled<<<dim3(2048 / 32, 512 / 32, NB_), 256, 0, stream>>>(ff_w1, ff1t, 512, 2048);
    transpose_tiled<<<dim3(512 / 32, 2048 / 32, NB_), 256, 0, stream>>>(ff_w2, ff2t, 2048, 512);

    embed_kernel<<<(M_ * 128) / 256, 256, 0, stream>>>(x, emb, pos, h);

    for (int i = 0; i < NB_; ++i) {
        ln_kernel<0><<<M_ / 4, 256, 0, stream>>>(h, ln1_g + i * 512, ln1_b + i * 512, xn);
        gemm_bt<128, 0, 0, 0, 1><<<dim3(M_ / 128, 1536 / 128), 256, 0, stream>>>(
            xn, wqkv_t + (size_t)i * 1536 * 512, nullptr, nullptr, qkvb, M_, 1536, 512);
        attn_kernel<<<dim3(B_ * NH_, 4), 256, 0, stream>>>(qkvb, aout);
        gemm_bt<64, 1, 1, 0, 0><<<dim3(M_ / 128, 512 / 64), 256, 0, stream>>>(
            aout, projt + (size_t)i * 512 * 512, proj_b + i * 512, h, h, M_, 512, 512);
        ln_kernel<0><<<M_ / 4, 256, 0, stream>>>(h, ln2_g + i * 512, ln2_b + i * 512, xn);
        gemm_bt<128, 1, 0, 1, 1><<<dim3(M_ / 128, 2048 / 128), 256, 0, stream>>>(
            xn, ff1t + (size_t)i * 2048 * 512, ff_b1 + i * 2048, nullptr, ffact, M_, 2048, 512);
        gemm_bt<64, 1, 1, 0, 0><<<dim3(M_ / 128, 512 / 64), 256, 0, stream>>>(
            ffact, ff2t + (size_t)i * 512 * 2048, ff_b2 + i * 512, h, h, M_, 512, 2048);
    }
    ln_kernel<1><<<M_ / 4, 256, 0, stream>>>(h, lnf_g, lnf_b, hn);
    outproj_kernel<<<(M_ * 16) / 256, 256, 0, stream>>>(hn, out_w, out_b, (float*)d_out);
}